// Round 3
// baseline (593.393 us; speedup 1.0000x reference)
//
#include <hip/hip_runtime.h>
#include <math.h>

#define M_SEQ 11520   // B*N
#define NNODE 360
#define NB    32
#define TT    64

// adj path: libm-accurate — gumbel/argmax pipeline bit-identical to proven state.
// GRU + decode: fast hardware exp (R12: absmax bit-unchanged).
__device__ __forceinline__ float fsigd(float x)  { return 1.0f / (1.0f + __expf(-x)); }
__device__ __forceinline__ float ftanhd(float x) { return 1.0f - 2.0f / (__expf(2.0f * x) + 1.0f); }

// ---------------- JAX threefry2x32, key=(0,42), partitionable, bits=y0^y1 ----
__device__ __forceinline__ unsigned rotl32(unsigned x, int n) { return (x << n) | (x >> (32 - n)); }

__device__ __forceinline__ void tf2x32(unsigned& x0, unsigned& x1)
{
    const unsigned k0 = 0u, k1 = 42u, k2 = 0u ^ 42u ^ 0x1BD11BDAu;
    x0 += k0; x1 += k1;
#define R4(a,b,c,d) \
    x0 += x1; x1 = rotl32(x1,a); x1 ^= x0; \
    x0 += x1; x1 = rotl32(x1,b); x1 ^= x0; \
    x0 += x1; x1 = rotl32(x1,c); x1 ^= x0; \
    x0 += x1; x1 = rotl32(x1,d); x1 ^= x0;
    R4(13,15,26,6)   x0 += k1; x1 += k2 + 1u;
    R4(17,29,16,24)  x0 += k2; x1 += k0 + 2u;
    R4(13,15,26,6)   x0 += k0; x1 += k1 + 3u;
    R4(17,29,16,24)  x0 += k1; x1 += k2 + 4u;
    R4(13,15,26,6)   x0 += k2; x1 += k0 + 5u;
#undef R4
}

__device__ __forceinline__ float jax_uniform(unsigned idx)
{
    unsigned x0 = 0u, x1 = idx;
    tf2x32(x0, x1);
    unsigned bits = x0 ^ x1;          // VERIFIED R5
    return __uint_as_float((bits >> 9) | 0x3f800000u) - 1.0f;
}

// broadcast within aligned 8-lane group via static-pattern ds_swizzle.
template<int K>
__device__ __forceinline__ void swz_fma(float h, const float* w0, const float* w1,
                                        const float* w2, float& g0, float& g1, float& g2)
{
    float hk = __int_as_float(
        __builtin_amdgcn_ds_swizzle(__float_as_int(h), (K << 5) | 0x18));
    g0 += hk * w0[K];
    g1 += hk * w1[K];
    g2 += hk * w2[K];
    if constexpr (K < 7)
        swz_fma<K + 1>(h, w0, w1, w2, g0, g1, g2);
}

// ---------------- GRU helpers (h-independent x-path separated) --------------
template<int I>
__device__ __forceinline__ void ldx(float* __restrict__ xv, const float* __restrict__ p)
{
    const float4* p4 = reinterpret_cast<const float4*>(p);
#pragma unroll
    for (int q = 0; q < I / 4; ++q) {
        float4 f = p4[q];
        xv[4*q] = f.x; xv[4*q+1] = f.y; xv[4*q+2] = f.z; xv[4*q+3] = f.w;
    }
}

template<int I>
__device__ __forceinline__ void xgates(const float* __restrict__ xv,
    const float* wx0, const float* wx1, const float* wx2,
    float bx0, float bx1, float bx2, float& xr, float& xz, float& xn)
{
    xr = bx0; xz = bx1; xn = bx2;   // same accumulation order as R12 -> bit-identical
#pragma unroll
    for (int k = 0; k < I; ++k) {
        xr += xv[k] * wx0[k];
        xz += xv[k] * wx1[k];
        xn += xv[k] * wx2[k];
    }
}

__device__ __forceinline__ float hstep(float h, float xr, float xz, float xn,
    const float* w0, const float* w1, const float* w2,
    float bh0, float bh1, float bh2)
{
    float gh0 = bh0, gh1 = bh1, gh2 = bh2;
    swz_fma<0>(h, w0, w1, w2, gh0, gh1, gh2);
    float r  = fsigd(xr + gh0);
    float z  = fsigd(xz + gh1);
    float nn = ftanhd(xn + r * gh2);
    return (1.f - z) * nn + z * h;
}

// ---------------- fused bidirectional GRU layer, 2-deep x pipeline ----------
// LASTONLY: final layer — only the t=TT-1 output slot is ever consumed
// (fwd: its last h, written at t1==TT-1; bwd: its first h, written at t0==TT-1).
template<int I, bool LASTONLY>
__global__ __launch_bounds__(256) void gru_fused(
    const float* __restrict__ x,    // (M,64,I)
    const float* __restrict__ wih,  // (2,24,I)
    const float* __restrict__ whh,  // (2,24,8)
    const float* __restrict__ bih,  // (2,24)
    const float* __restrict__ bhh,  // (2,24)
    float* __restrict__ out)        // (M,64,16), dir writes its 8-half
{
    const int tid = blockIdx.x * 256 + threadIdx.x;
    const int j   = tid & 7;
    const int md  = tid >> 3;
    if (md >= M_SEQ * 2) return;
    const int m = md >> 1, dir = md & 1;

    float wx0[I], wx1[I], wx2[I];
    const float* WI = wih + dir * 24 * I;
#pragma unroll
    for (int k = 0; k < I; ++k) {
        wx0[k] = WI[j * I + k];
        wx1[k] = WI[(8 + j) * I + k];
        wx2[k] = WI[(16 + j) * I + k];
    }
    float w0[8], w1[8], w2[8];
    const float* WH = whh + dir * 192;
#pragma unroll
    for (int k = 0; k < 8; ++k) {
        w0[k] = WH[j * 8 + k];
        w1[k] = WH[(8 + j) * 8 + k];
        w2[k] = WH[(16 + j) * 8 + k];
    }
    const float bx0 = bih[dir*24 + j], bx1 = bih[dir*24 + 8 + j], bx2 = bih[dir*24 + 16 + j];
    const float bh0 = bhh[dir*24 + j], bh1 = bhh[dir*24 + 8 + j], bh2 = bhh[dir*24 + 16 + j];

    const float* xm = x + (size_t)m * TT * I;
    float* om = out + (size_t)m * TT * 16 + dir * 8 + j;

    const int tstep = dir ? -1 : 1;
    const int tbase = dir ? TT - 1 : 0;

    float h = 0.f;
    float xva[I], xvb[I];
    ldx<I>(xva, xm + (tbase) * I);                 // t(0)
    ldx<I>(xvb, xm + (tbase + tstep) * I);         // t(1)
    float cr, cz, cn;
    xgates<I>(xva, wx0, wx1, wx2, bx0, bx1, bx2, cr, cz, cn);   // gates(t(0))

    for (int tt = 0; tt < TT; tt += 2) {
        const int t0 = tbase + tstep * tt;
        const int t1 = t0 + tstep;
        // prefetch t(tt+2) into the slot whose data is already in c-gates
        if (tt + 2 < TT) ldx<I>(xva, xm + (t0 + 2 * tstep) * I);
        // gates(t(tt+1)) — h-independent, overlaps the recurrence stalls
        float nr, nz, nn;
        xgates<I>(xvb, wx0, wx1, wx2, bx0, bx1, bx2, nr, nz, nn);
        h = hstep(h, cr, cz, cn, w0, w1, w2, bh0, bh1, bh2);
        if (!LASTONLY || t0 == TT - 1) om[t0 * 16] = h;
        // prefetch t(tt+3); xvb's content was consumed into n-gates above
        if (tt + 3 < TT) ldx<I>(xvb, xm + (t0 + 3 * tstep) * I);
        h = hstep(h, nr, nz, nn, w0, w1, w2, bh0, bh1, bh2);
        if (!LASTONLY || t1 == TT - 1) om[t1 * 16] = h;
        // gates(t(tt+2)) from xva — placed last: max load->use distance
        xgates<I>(xva, wx0, wx1, wx2, bx0, bx1, bx2, cr, cz, cn);
    }
}

// ---------------- feat MLP (pure FMA) ---------------------------------------
__global__ void feat_kernel(const float* __restrict__ gout,
                            const float* __restrict__ l1w, const float* __restrict__ l1b,
                            const float* __restrict__ l2w, const float* __restrict__ l2b,
                            float* __restrict__ feat)
{
    int m = blockIdx.x * blockDim.x + threadIdx.x;
    if (m >= M_SEQ) return;
    const float* xp = gout + (size_t)m * TT * 16 + (TT - 1) * 16;
    float xv[16];
#pragma unroll
    for (int i = 0; i < 16; ++i) xv[i] = xp[i];
    float h1[8];
#pragma unroll
    for (int o = 0; o < 8; ++o) {
        float a = 0.f;
#pragma unroll
        for (int f = 0; f < 16; ++f) a += xv[f] * l1w[o * 16 + f];
        a += l1b[o];
        h1[o] = (a >= 0.f) ? a : 0.2f * a;
    }
#pragma unroll
    for (int o = 0; o < 8; ++o) {
        float a = 0.f;
#pragma unroll
        for (int f = 0; f < 8; ++f) a += h1[f] * l2w[o * 8 + f];
        feat[(size_t)m * 8 + o] = a + l2b[o];
    }
}

// ---------------- adjacency (libm — bit-identical to proven state) ----------
__global__ void adj_kernel(const float* __restrict__ feat,
                           const float* __restrict__ tptr,
                           int* __restrict__ colp, float* __restrict__ vp)
{
    const int gw   = (blockIdx.x * blockDim.x + threadIdx.x) >> 6;
    const int lane = threadIdx.x & 63;
    if (gw >= NB * NNODE) return;
    const int b = gw / NNODE;
    const int n = gw - b * NNODE;
    const float T = tptr[0];
    const float* fb = feat + (size_t)b * NNODE * 8;
    float fn[8];
#pragma unroll
    for (int k = 0; k < 8; ++k) fn[k] = fb[(size_t)n * 8 + k];

    float sv[6];
    float mval = -3.0e38f; int midx = 1 << 30;
#pragma unroll
    for (int s = 0; s < 6; ++s) {
        int p = s * 64 + lane;
        float xs = -3.0e38f;
        if (p < NNODE) {
            const float* fp = fb + (size_t)p * 8;
            float d = 0.f;
#pragma unroll
            for (int k = 0; k < 8; ++k) d += fn[k] * fp[k];
            unsigned idx = (unsigned)gw * 360u + (unsigned)p;
            float u   = jax_uniform(idx);
            float gum = -logf(-logf(u + 1e-10f) + 1e-10f);
            xs = (d + gum) / T;
            if (xs > mval) { mval = xs; midx = p; }
        }
        sv[s] = xs;
    }
    for (int off = 32; off > 0; off >>= 1) {   // ties -> smaller index
        float ov = __shfl_xor(mval, off);
        int   oi = __shfl_xor(midx, off);
        if (ov > mval || (ov == mval && oi < midx)) { mval = ov; midx = oi; }
    }
    float ssum = 0.f;
#pragma unroll
    for (int s = 0; s < 6; ++s) {
        int p = s * 64 + lane;
        if (p < NNODE) ssum += expf(sv[s] - mval);
    }
    for (int off = 32; off > 0; off >>= 1) ssum += __shfl_xor(ssum, off);
    if (lane == 0) {
        float ys = 1.0f / ssum;
        float v  = ys + (1.0f - ys);
        if (midx == n) v = 0.0f;
        colp[gw] = midx;
        vp[gw]   = v;
    }
}

// ---------------- DCGRU cell, redundant-r form (bit-exact, verified R1) ------
// Thread n computes its own r,u,c AND redundantly recomputes r at c1,c2 from
// gathered o/h at c1..c4 (one-hot adjacency => closure is the col-chain).
// Same formula order as the owning thread => bit-identical values.
__device__ __forceinline__ float dc_cell(
    float o, float o1, float o2, float o3, float o4,
    float h, float h1, float h2, float h3, float h4,
    float v, float vv, float va, float vva, float vb, float vvb,
    const float* __restrict__ W, float bgr, float bgu,
    const float* __restrict__ C, float cb)
{
    float f1 = v * o1,  f2 = vv * o2 - o;
    float f4 = v * h1,  f5 = vv * h2 - h;
    float r  = fsigd(o*W[0] + f1*W[2] + f2*W[4] + h*W[6] + f4*W[8] + f5*W[10] + bgr);
    float u  = fsigd(o*W[1] + f1*W[3] + f2*W[5] + h*W[7] + f4*W[9] + f5*W[11] + bgu);
    float rh = r * h;
    // redundant r at c1 (node c1's own v is va, its vv is vva)
    float g1 = va * o2, g2 = vva * o3 - o1;
    float g4 = va * h2, g5 = vva * h3 - h1;
    float ra = fsigd(o1*W[0] + g1*W[2] + g2*W[4] + h1*W[6] + g4*W[8] + g5*W[10] + bgr);
    float rha = ra * h1;
    // redundant r at c2
    float k1 = vb * o3, k2 = vvb * o4 - o2;
    float k4 = vb * h3, k5 = vvb * h4 - h2;
    float rb = fsigd(o2*W[0] + k1*W[2] + k2*W[4] + h2*W[6] + k4*W[8] + k5*W[10] + bgr);
    float rhb = rb * h2;
    float cnd = ftanhd(o*C[0] + f1*C[1] + f2*C[2] + rh*C[3]
                       + (v*rha)*C[4] + (vv*rhb - rh)*C[5] + cb);
    return u * h + (1.f - u) * cnd;
}

// decode R3: scalar LDS layout (R2, conflict-free) + redundant-r (R1, verified)
//  -> 1 barrier + 1 exposed LDS roundtrip per layer (3/step, was 6/step).
//  All prev-step gathers (x,h0,h1,h2 at c1..c4 = 16 scalar reads) issue
//  together at step top; weights live in SGPRs; s_oA/s_oB alternate per layer
//  so the single-barrier scheme has no write-after-read hazard.
__global__ __launch_bounds__(384, 1) void decode_kernel(
    const float* __restrict__ rec,   // (B, N, T)
    const int*   __restrict__ colp, const float* __restrict__ vp,
    const float* __restrict__ egw, const float* __restrict__ egb,
    const float* __restrict__ ecw, const float* __restrict__ ecb,
    const float* __restrict__ dgw, const float* __restrict__ dgb,
    const float* __restrict__ dcw, const float* __restrict__ dcb,
    const float* __restrict__ pw,  const float* __restrict__ pb,
    float* __restrict__ outp)        // (B, N, T)
{
    __shared__ float s_h[2][3][NNODE];   // [parity][layer][node], 4B stride
    __shared__ float s_x[2][NNODE];      // [parity][node] layer-0 input staging
    __shared__ float s_oA[NNODE];        // layer-0 output exchange
    __shared__ float s_oB[NNODE];        // layer-1 output exchange
    __shared__ float s_v[NNODE];
    __shared__ int   s_c[NNODE];

    const int b = blockIdx.x;
    const int n = threadIdx.x;
    const bool act = n < NNODE;

    float inp0 = 0.f;
    if (act) {
        s_c[n] = colp[b * NNODE + n];
        s_v[n] = vp[b * NNODE + n];
        inp0   = rec[((size_t)b * NNODE + n) * TT + 0];
        s_h[0][0][n] = 0.f; s_h[0][1][n] = 0.f; s_h[0][2][n] = 0.f;
        s_x[0][n] = inp0;
    }
    __syncthreads();

    int c1 = 0, c2 = 0, c3 = 0, c4 = 0;
    float v = 0.f, vv = 0.f, va = 0.f, vva = 0.f, vb = 0.f, vvb = 0.f;
    if (act) {
        c1 = s_c[n]; c2 = s_c[c1]; c3 = s_c[c2]; c4 = s_c[c3];
        v  = s_v[n];
        float sv1 = s_v[c1], sv2 = s_v[c2], sv3 = s_v[c3];
        vv  = 2.f * v   * sv1;
        va  = sv1; vva = 2.f * sv1 * sv2;
        vb  = sv2; vvb = 2.f * sv2 * sv3;
    }
    const float projw = pw[0], projb = pb[0];
    float hreg[3] = {0.f, 0.f, 0.f};

    // ---- encoder weights -> registers (uniform loads -> SGPRs) ----
    float Wg[36], Bg[6], Wc[18], Cb[3];
#pragma unroll
    for (int k = 0; k < 36; ++k) Wg[k] = egw[k];
#pragma unroll
    for (int k = 0; k < 6;  ++k) Bg[k] = egb[k];
#pragma unroll
    for (int k = 0; k < 18; ++k) Wc[k] = ecw[k];
#pragma unroll
    for (int k = 0; k < 3;  ++k) Cb[k] = ecb[k];

    float o_own = inp0;
    int p = 0;
    // ---------------- encoder ----------------
    for (int t = 0; t < TT; ++t) {
        float nx = (act && t + 1 < TT) ? rec[((size_t)b * NNODE + n) * TT + t + 1] : 0.f;
        // all previous-step-state gathers issue together (parity p read-only)
        float xa=0.f,xb=0.f,xc=0.f,xd=0.f;
        float h0a=0.f,h0b=0.f,h0c=0.f,h0d=0.f;
        float h1a=0.f,h1b=0.f,h1c=0.f,h1d=0.f;
        float h2a=0.f,h2b=0.f,h2c=0.f,h2d=0.f;
        if (act) {
            xa  = s_x[p][c1];    xb  = s_x[p][c2];    xc  = s_x[p][c3];    xd  = s_x[p][c4];
            h0a = s_h[p][0][c1]; h0b = s_h[p][0][c2]; h0c = s_h[p][0][c3]; h0d = s_h[p][0][c4];
            h1a = s_h[p][1][c1]; h1b = s_h[p][1][c2]; h1c = s_h[p][1][c3]; h1d = s_h[p][1][c4];
            h2a = s_h[p][2][c1]; h2b = s_h[p][2][c2]; h2c = s_h[p][2][c3]; h2d = s_h[p][2][c4];
        }
        const int q = p ^ 1;
        // layer 0
        float hn0 = dc_cell(o_own, xa, xb, xc, xd,
                            hreg[0], h0a, h0b, h0c, h0d,
                            v, vv, va, vva, vb, vvb, Wg, Bg[0], Bg[1], Wc, Cb[0]);
        hreg[0] = hn0;
        if (act) { s_h[q][0][n] = hn0; s_oA[n] = hn0; }
        __syncthreads();
        // layer 1
        float oa=0.f, ob=0.f, oc=0.f, od=0.f;
        if (act) { oa = s_oA[c1]; ob = s_oA[c2]; oc = s_oA[c3]; od = s_oA[c4]; }
        float hn1 = dc_cell(hn0, oa, ob, oc, od,
                            hreg[1], h1a, h1b, h1c, h1d,
                            v, vv, va, vva, vb, vvb, Wg + 12, Bg[2], Bg[3], Wc + 6, Cb[1]);
        hreg[1] = hn1;
        if (act) { s_h[q][1][n] = hn1; s_oB[n] = hn1; }
        __syncthreads();
        // layer 2
        if (act) { oa = s_oB[c1]; ob = s_oB[c2]; oc = s_oB[c3]; od = s_oB[c4]; }
        float hn2 = dc_cell(hn1, oa, ob, oc, od,
                            hreg[2], h2a, h2b, h2c, h2d,
                            v, vv, va, vva, vb, vvb, Wg + 24, Bg[4], Bg[5], Wc + 12, Cb[2]);
        hreg[2] = hn2;
        if (act) { s_h[q][2][n] = hn2; s_x[q][n] = nx; }  // stage next input
        __syncthreads();
        o_own = nx; p = q;
    }
    // 64 steps -> p back to 0; s_x[0][n] == 0 == first decoder input.

    // ---- decoder weights -> registers ----
#pragma unroll
    for (int k = 0; k < 36; ++k) Wg[k] = dgw[k];
#pragma unroll
    for (int k = 0; k < 6;  ++k) Bg[k] = dgb[k];
#pragma unroll
    for (int k = 0; k < 18; ++k) Wc[k] = dcw[k];
#pragma unroll
    for (int k = 0; k < 3;  ++k) Cb[k] = dcb[k];

    // ---------------- decoder ----------------
    float dinp = 0.f;
    for (int t = 0; t < TT; ++t) {
        float xa=0.f,xb=0.f,xc=0.f,xd=0.f;
        float h0a=0.f,h0b=0.f,h0c=0.f,h0d=0.f;
        float h1a=0.f,h1b=0.f,h1c=0.f,h1d=0.f;
        float h2a=0.f,h2b=0.f,h2c=0.f,h2d=0.f;
        if (act) {
            xa  = s_x[p][c1];    xb  = s_x[p][c2];    xc  = s_x[p][c3];    xd  = s_x[p][c4];
            h0a = s_h[p][0][c1]; h0b = s_h[p][0][c2]; h0c = s_h[p][0][c3]; h0d = s_h[p][0][c4];
            h1a = s_h[p][1][c1]; h1b = s_h[p][1][c2]; h1c = s_h[p][1][c3]; h1d = s_h[p][1][c4];
            h2a = s_h[p][2][c1]; h2b = s_h[p][2][c2]; h2c = s_h[p][2][c3]; h2d = s_h[p][2][c4];
        }
        const int q = p ^ 1;
        float hn0 = dc_cell(dinp, xa, xb, xc, xd,
                            hreg[0], h0a, h0b, h0c, h0d,
                            v, vv, va, vva, vb, vvb, Wg, Bg[0], Bg[1], Wc, Cb[0]);
        hreg[0] = hn0;
        if (act) { s_h[q][0][n] = hn0; s_oA[n] = hn0; }
        __syncthreads();
        float oa=0.f, ob=0.f, oc=0.f, od=0.f;
        if (act) { oa = s_oA[c1]; ob = s_oA[c2]; oc = s_oA[c3]; od = s_oA[c4]; }
        float hn1 = dc_cell(hn0, oa, ob, oc, od,
                            hreg[1], h1a, h1b, h1c, h1d,
                            v, vv, va, vva, vb, vvb, Wg + 12, Bg[2], Bg[3], Wc + 6, Cb[1]);
        hreg[1] = hn1;
        if (act) { s_h[q][1][n] = hn1; s_oB[n] = hn1; }
        __syncthreads();
        if (act) { oa = s_oB[c1]; ob = s_oB[c2]; oc = s_oB[c3]; od = s_oB[c4]; }
        float hn2 = dc_cell(hn1, oa, ob, oc, od,
                            hreg[2], h2a, h2b, h2c, h2d,
                            v, vv, va, vva, vb, vvb, Wg + 24, Bg[4], Bg[5], Wc + 12, Cb[2]);
        hreg[2] = hn2;
        float proj = hn2 * projw + projb;
        if (act) {
            s_h[q][2][n] = hn2;
            s_x[q][n] = proj;                    // stage next decoder input
            outp[((size_t)b * NNODE + n) * TT + t] = proj;
        }
        __syncthreads();
        dinp = proj; p = q;
    }
}

// ---------------- host launcher ---------------------------------------------
extern "C" void kernel_launch(void* const* d_in, const int* in_sizes, int n_in,
                              void* d_out, int out_size, void* d_ws, size_t ws_size,
                              hipStream_t stream)
{
    (void)in_sizes; (void)n_in; (void)out_size; (void)ws_size;
    const float* full_seq = (const float*)d_in[0];   // (M,64,8)
    const float* rec_seq  = (const float*)d_in[1];   // (32,360,64)
    const float* temp     = (const float*)d_in[3];
    const float* g0wih    = (const float*)d_in[4];
    const float* g0whh    = (const float*)d_in[5];
    const float* g0bih    = (const float*)d_in[6];
    const float* g0bhh    = (const float*)d_in[7];
    const float* gwih     = (const float*)d_in[8];   // (3,2,24,16)
    const float* gwhh     = (const float*)d_in[9];   // (3,2,24,8)
    const float* gbih     = (const float*)d_in[10];
    const float* gbhh     = (const float*)d_in[11];
    const float* l1w      = (const float*)d_in[12];
    const float* l1b      = (const float*)d_in[13];
    const float* l2w      = (const float*)d_in[14];
    const float* l2b      = (const float*)d_in[15];
    const float* enc_gw   = (const float*)d_in[16];
    const float* enc_gb   = (const float*)d_in[17];
    const float* enc_cw   = (const float*)d_in[18];
    const float* enc_cb   = (const float*)d_in[19];
    const float* dec_gw   = (const float*)d_in[20];
    const float* dec_gb   = (const float*)d_in[21];
    const float* dec_cw   = (const float*)d_in[22];
    const float* dec_cb   = (const float*)d_in[23];
    const float* proj_w   = (const float*)d_in[24];
    const float* proj_b   = (const float*)d_in[25];
    float* outp = (float*)d_out;

    // ws: small-first; bufA+bufB ping-pong = 94.85 MB total (proven size)
    float* ws   = (float*)d_ws;
    float* feat = ws;                                     // (M,8)
    float* vbuf = feat + (size_t)M_SEQ * 8;               // (M,)
    int*   cbuf = (int*)(vbuf + M_SEQ);                   // (M,)
    float* bufA = (float*)(cbuf + M_SEQ);                 // (M,64,16)
    float* bufB = bufA + (size_t)M_SEQ * TT * 16;         // (M,64,16)

    const int ggru = (M_SEQ * 2 * 8) / 256;   // 720 blocks
    gru_fused<8,false><<<ggru, 256, 0, stream>>>(full_seq, g0wih, g0whh, g0bih, g0bhh, bufA);
    gru_fused<16,false><<<ggru, 256, 0, stream>>>(bufA, gwih + 0 * 768, gwhh + 0 * 384,
                                                  gbih + 0 * 48, gbhh + 0 * 48, bufB);
    gru_fused<16,false><<<ggru, 256, 0, stream>>>(bufB, gwih + 1 * 768, gwhh + 1 * 384,
                                                  gbih + 1 * 48, gbhh + 1 * 48, bufA);
    gru_fused<16,true><<<ggru, 256, 0, stream>>>(bufA, gwih + 2 * 768, gwhh + 2 * 384,
                                                 gbih + 2 * 48, gbhh + 2 * 48, bufB);
    feat_kernel<<<M_SEQ / 256, 256, 0, stream>>>(bufB, l1w, l1b, l2w, l2b, feat);
    adj_kernel<<<(NB * NNODE) / 4, 256, 0, stream>>>(feat, temp, cbuf, vbuf);
    decode_kernel<<<NB, 384, 0, stream>>>(rec_seq, cbuf, vbuf,
                                          enc_gw, enc_gb, enc_cw, enc_cb,
                                          dec_gw, dec_gb, dec_cw, dec_cb,
                                          proj_w, proj_b, outp);
}

// Round 4
// 547.279 us; speedup vs baseline: 1.0843x; 1.0843x over previous
//
#include <hip/hip_runtime.h>
#include <math.h>

#define M_SEQ 11520   // B*N
#define NNODE 360
#define NB    32
#define TT    64

// adj path: libm-accurate — gumbel/argmax pipeline bit-identical to proven state.
// GRU + decode: fast hardware exp (R12: absmax bit-unchanged).
__device__ __forceinline__ float fsigd(float x)  { return 1.0f / (1.0f + __expf(-x)); }
__device__ __forceinline__ float ftanhd(float x) { return 1.0f - 2.0f / (__expf(2.0f * x) + 1.0f); }

// ---------------- JAX threefry2x32, key=(0,42), partitionable, bits=y0^y1 ----
__device__ __forceinline__ unsigned rotl32(unsigned x, int n) { return (x << n) | (x >> (32 - n)); }

__device__ __forceinline__ void tf2x32(unsigned& x0, unsigned& x1)
{
    const unsigned k0 = 0u, k1 = 42u, k2 = 0u ^ 42u ^ 0x1BD11BDAu;
    x0 += k0; x1 += k1;
#define R4(a,b,c,d) \
    x0 += x1; x1 = rotl32(x1,a); x1 ^= x0; \
    x0 += x1; x1 = rotl32(x1,b); x1 ^= x0; \
    x0 += x1; x1 = rotl32(x1,c); x1 ^= x0; \
    x0 += x1; x1 = rotl32(x1,d); x1 ^= x0;
    R4(13,15,26,6)   x0 += k1; x1 += k2 + 1u;
    R4(17,29,16,24)  x0 += k2; x1 += k0 + 2u;
    R4(13,15,26,6)   x0 += k0; x1 += k1 + 3u;
    R4(17,29,16,24)  x0 += k1; x1 += k2 + 4u;
    R4(13,15,26,6)   x0 += k2; x1 += k0 + 5u;
#undef R4
}

__device__ __forceinline__ float jax_uniform(unsigned idx)
{
    unsigned x0 = 0u, x1 = idx;
    tf2x32(x0, x1);
    unsigned bits = x0 ^ x1;          // VERIFIED R5
    return __uint_as_float((bits >> 9) | 0x3f800000u) - 1.0f;
}

// broadcast within aligned 8-lane group via static-pattern ds_swizzle.
template<int K>
__device__ __forceinline__ void swz_fma(float h, const float* w0, const float* w1,
                                        const float* w2, float& g0, float& g1, float& g2)
{
    float hk = __int_as_float(
        __builtin_amdgcn_ds_swizzle(__float_as_int(h), (K << 5) | 0x18));
    g0 += hk * w0[K];
    g1 += hk * w1[K];
    g2 += hk * w2[K];
    if constexpr (K < 7)
        swz_fma<K + 1>(h, w0, w1, w2, g0, g1, g2);
}

// ---------------- GRU helpers (h-independent x-path separated) --------------
template<int I>
__device__ __forceinline__ void ldx(float* __restrict__ xv, const float* __restrict__ p)
{
    const float4* p4 = reinterpret_cast<const float4*>(p);
#pragma unroll
    for (int q = 0; q < I / 4; ++q) {
        float4 f = p4[q];
        xv[4*q] = f.x; xv[4*q+1] = f.y; xv[4*q+2] = f.z; xv[4*q+3] = f.w;
    }
}

template<int I>
__device__ __forceinline__ void xgates(const float* __restrict__ xv,
    const float* wx0, const float* wx1, const float* wx2,
    float bx0, float bx1, float bx2, float& xr, float& xz, float& xn)
{
    xr = bx0; xz = bx1; xn = bx2;   // same accumulation order as R12 -> bit-identical
#pragma unroll
    for (int k = 0; k < I; ++k) {
        xr += xv[k] * wx0[k];
        xz += xv[k] * wx1[k];
        xn += xv[k] * wx2[k];
    }
}

__device__ __forceinline__ float hstep(float h, float xr, float xz, float xn,
    const float* w0, const float* w1, const float* w2,
    float bh0, float bh1, float bh2)
{
    float gh0 = bh0, gh1 = bh1, gh2 = bh2;
    swz_fma<0>(h, w0, w1, w2, gh0, gh1, gh2);
    float r  = fsigd(xr + gh0);
    float z  = fsigd(xz + gh1);
    float nn = ftanhd(xn + r * gh2);
    return (1.f - z) * nn + z * h;
}

// ---------------- fused bidirectional GRU layer, 2-deep x pipeline ----------
// LASTONLY: final layer — only the t=TT-1 output slot is ever consumed
// (fwd: its last h, written at t1==TT-1; bwd: its first h, written at t0==TT-1).
template<int I, bool LASTONLY>
__global__ __launch_bounds__(256) void gru_fused(
    const float* __restrict__ x,    // (M,64,I)
    const float* __restrict__ wih,  // (2,24,I)
    const float* __restrict__ whh,  // (2,24,8)
    const float* __restrict__ bih,  // (2,24)
    const float* __restrict__ bhh,  // (2,24)
    float* __restrict__ out)        // (M,64,16), dir writes its 8-half
{
    const int tid = blockIdx.x * 256 + threadIdx.x;
    const int j   = tid & 7;
    const int md  = tid >> 3;
    if (md >= M_SEQ * 2) return;
    const int m = md >> 1, dir = md & 1;

    float wx0[I], wx1[I], wx2[I];
    const float* WI = wih + dir * 24 * I;
#pragma unroll
    for (int k = 0; k < I; ++k) {
        wx0[k] = WI[j * I + k];
        wx1[k] = WI[(8 + j) * I + k];
        wx2[k] = WI[(16 + j) * I + k];
    }
    float w0[8], w1[8], w2[8];
    const float* WH = whh + dir * 192;
#pragma unroll
    for (int k = 0; k < 8; ++k) {
        w0[k] = WH[j * 8 + k];
        w1[k] = WH[(8 + j) * 8 + k];
        w2[k] = WH[(16 + j) * 8 + k];
    }
    const float bx0 = bih[dir*24 + j], bx1 = bih[dir*24 + 8 + j], bx2 = bih[dir*24 + 16 + j];
    const float bh0 = bhh[dir*24 + j], bh1 = bhh[dir*24 + 8 + j], bh2 = bhh[dir*24 + 16 + j];

    const float* xm = x + (size_t)m * TT * I;
    float* om = out + (size_t)m * TT * 16 + dir * 8 + j;

    const int tstep = dir ? -1 : 1;
    const int tbase = dir ? TT - 1 : 0;

    float h = 0.f;
    float xva[I], xvb[I];
    ldx<I>(xva, xm + (tbase) * I);                 // t(0)
    ldx<I>(xvb, xm + (tbase + tstep) * I);         // t(1)
    float cr, cz, cn;
    xgates<I>(xva, wx0, wx1, wx2, bx0, bx1, bx2, cr, cz, cn);   // gates(t(0))

    for (int tt = 0; tt < TT; tt += 2) {
        const int t0 = tbase + tstep * tt;
        const int t1 = t0 + tstep;
        // prefetch t(tt+2) into the slot whose data is already in c-gates
        if (tt + 2 < TT) ldx<I>(xva, xm + (t0 + 2 * tstep) * I);
        // gates(t(tt+1)) — h-independent, overlaps the recurrence stalls
        float nr, nz, nn;
        xgates<I>(xvb, wx0, wx1, wx2, bx0, bx1, bx2, nr, nz, nn);
        h = hstep(h, cr, cz, cn, w0, w1, w2, bh0, bh1, bh2);
        if (!LASTONLY || t0 == TT - 1) om[t0 * 16] = h;
        // prefetch t(tt+3); xvb's content was consumed into n-gates above
        if (tt + 3 < TT) ldx<I>(xvb, xm + (t0 + 3 * tstep) * I);
        h = hstep(h, nr, nz, nn, w0, w1, w2, bh0, bh1, bh2);
        if (!LASTONLY || t1 == TT - 1) om[t1 * 16] = h;
        // gates(t(tt+2)) from xva — placed last: max load->use distance
        xgates<I>(xva, wx0, wx1, wx2, bx0, bx1, bx2, cr, cz, cn);
    }
}

// ---------------- feat MLP (pure FMA) ---------------------------------------
__global__ void feat_kernel(const float* __restrict__ gout,
                            const float* __restrict__ l1w, const float* __restrict__ l1b,
                            const float* __restrict__ l2w, const float* __restrict__ l2b,
                            float* __restrict__ feat)
{
    int m = blockIdx.x * blockDim.x + threadIdx.x;
    if (m >= M_SEQ) return;
    const float* xp = gout + (size_t)m * TT * 16 + (TT - 1) * 16;
    float xv[16];
#pragma unroll
    for (int i = 0; i < 16; ++i) xv[i] = xp[i];
    float h1[8];
#pragma unroll
    for (int o = 0; o < 8; ++o) {
        float a = 0.f;
#pragma unroll
        for (int f = 0; f < 16; ++f) a += xv[f] * l1w[o * 16 + f];
        a += l1b[o];
        h1[o] = (a >= 0.f) ? a : 0.2f * a;
    }
#pragma unroll
    for (int o = 0; o < 8; ++o) {
        float a = 0.f;
#pragma unroll
        for (int f = 0; f < 8; ++f) a += h1[f] * l2w[o * 8 + f];
        feat[(size_t)m * 8 + o] = a + l2b[o];
    }
}

// ---------------- adjacency (libm — bit-identical to proven state) ----------
__global__ void adj_kernel(const float* __restrict__ feat,
                           const float* __restrict__ tptr,
                           int* __restrict__ colp, float* __restrict__ vp)
{
    const int gw   = (blockIdx.x * blockDim.x + threadIdx.x) >> 6;
    const int lane = threadIdx.x & 63;
    if (gw >= NB * NNODE) return;
    const int b = gw / NNODE;
    const int n = gw - b * NNODE;
    const float T = tptr[0];
    const float* fb = feat + (size_t)b * NNODE * 8;
    float fn[8];
#pragma unroll
    for (int k = 0; k < 8; ++k) fn[k] = fb[(size_t)n * 8 + k];

    float sv[6];
    float mval = -3.0e38f; int midx = 1 << 30;
#pragma unroll
    for (int s = 0; s < 6; ++s) {
        int p = s * 64 + lane;
        float xs = -3.0e38f;
        if (p < NNODE) {
            const float* fp = fb + (size_t)p * 8;
            float d = 0.f;
#pragma unroll
            for (int k = 0; k < 8; ++k) d += fn[k] * fp[k];
            unsigned idx = (unsigned)gw * 360u + (unsigned)p;
            float u   = jax_uniform(idx);
            float gum = -logf(-logf(u + 1e-10f) + 1e-10f);
            xs = (d + gum) / T;
            if (xs > mval) { mval = xs; midx = p; }
        }
        sv[s] = xs;
    }
    for (int off = 32; off > 0; off >>= 1) {   // ties -> smaller index
        float ov = __shfl_xor(mval, off);
        int   oi = __shfl_xor(midx, off);
        if (ov > mval || (ov == mval && oi < midx)) { mval = ov; midx = oi; }
    }
    float ssum = 0.f;
#pragma unroll
    for (int s = 0; s < 6; ++s) {
        int p = s * 64 + lane;
        if (p < NNODE) ssum += expf(sv[s] - mval);
    }
    for (int off = 32; off > 0; off >>= 1) ssum += __shfl_xor(ssum, off);
    if (lane == 0) {
        float ys = 1.0f / ssum;
        float v  = ys + (1.0f - ys);
        if (midx == n) v = 0.0f;
        colp[gw] = midx;
        vp[gw]   = v;
    }
}

// ---------------- DCGRU layer: R2-proven arithmetic --------------------------
// Expressions and evaluation order IDENTICAL to R2 -> bit-identical results.
// rh gathers issue before u is computed, so u's VALU hides under LDS latency.
__device__ __forceinline__ void dc_layer(
    float o_own, float oa, float ob,          // layer input at n, c1, c2
    float& hn, float ha, float hb,            // layer state at n (updated), c1, c2
    float v, float vv, int c1, int c2, bool act, int n,
    const float* __restrict__ W, float bgr, float bgu,
    const float* __restrict__ C, float cb,
    float* __restrict__ s_rh)
{
    float f1 = v * oa, f2 = vv * ob - o_own;
    float f4 = v * ha, f5 = vv * hb - hn;
    float r  = fsigd(o_own*W[0] + f1*W[2] + f2*W[4] + hn*W[6] + f4*W[8] + f5*W[10] + bgr);
    float rh = r * hn;
    if (act) s_rh[n] = rh;
    __syncthreads();
    // issue gathers first, then compute u (independent of r) under the latency
    float rha = s_rh[c1], rhb = s_rh[c2];
    float u  = fsigd(o_own*W[1] + f1*W[3] + f2*W[5] + hn*W[7] + f4*W[9] + f5*W[11] + bgu);
    float cnd = ftanhd(o_own*C[0] + f1*C[1] + f2*C[2] + rh*C[3]
                       + (v*rha)*C[4] + (vv*rhb - rh)*C[5] + cb);
    hn = u * hn + (1.f - u) * cnd;
}

// decode R4: R2's proven structure (6 barriers/step, scalar LDS, hoisted
// gathers, SGPR weights) with the steady-state loop made GLOBAL-FREE:
//  - rec staged once into s_big[t][node] (stride 361) -> no global load in
//    the encoder loop crossing a barrier (each __syncthreads drains vmcnt(0))
//  - decoder proj written to s_big rows (buffer reused), gathered from row
//    t-1 next step; one coalesced LDS->global writeout at the end.
__global__ __launch_bounds__(384, 1) void decode_kernel(
    const float* __restrict__ rec,   // (B, N, T)
    const int*   __restrict__ colp, const float* __restrict__ vp,
    const float* __restrict__ egw, const float* __restrict__ egb,
    const float* __restrict__ ecw, const float* __restrict__ ecb,
    const float* __restrict__ dgw, const float* __restrict__ dgb,
    const float* __restrict__ dcw, const float* __restrict__ dcb,
    const float* __restrict__ pw,  const float* __restrict__ pb,
    float* __restrict__ outp)        // (B, N, T)
{
    __shared__ float s_big[TT * 361];    // [t][node], stride 361 (writeout 2-way)
    __shared__ float s_h[2][3][NNODE];   // [parity][layer][node], 4B stride
    __shared__ float s_o[NNODE];         // intra-step layer output exchange
    __shared__ float s_rh[NNODE];
    __shared__ float s_v[NNODE];
    __shared__ int   s_c[NNODE];

    const int b = blockIdx.x;
    const int n = threadIdx.x;
    const bool act = n < NNODE;

    // ---- stage rec row-block into LDS, transposed (one-time, off chain) ----
    for (int f = threadIdx.x; f < (NNODE * TT) / 4; f += 384) {
        const int nn = f >> 4;            // node
        const int t4 = (f & 15) << 2;     // t base
        float4 r4 = *reinterpret_cast<const float4*>(
            rec + ((size_t)b * NNODE + nn) * TT + t4);
        s_big[(t4 + 0) * 361 + nn] = r4.x;
        s_big[(t4 + 1) * 361 + nn] = r4.y;
        s_big[(t4 + 2) * 361 + nn] = r4.z;
        s_big[(t4 + 3) * 361 + nn] = r4.w;
    }
    if (act) {
        s_c[n] = colp[b * NNODE + n];
        s_v[n] = vp[b * NNODE + n];
        s_h[0][0][n] = 0.f; s_h[0][1][n] = 0.f; s_h[0][2][n] = 0.f;
    }
    __syncthreads();

    int c1 = 0, c2 = 0;
    float v = 0.f, vv = 0.f;
    if (act) {
        c1 = s_c[n];
        c2 = s_c[c1];
        v  = s_v[n];
        vv = 2.f * v * s_v[c1];
    }
    const float projw = pw[0], projb = pb[0];
    float hreg[3] = {0.f, 0.f, 0.f};

    // ---- encoder weights -> registers (uniform loads -> SGPRs) ----
    float Wg[36], Bg[6], Wc[18], Cb[3];
#pragma unroll
    for (int k = 0; k < 36; ++k) Wg[k] = egw[k];
#pragma unroll
    for (int k = 0; k < 6;  ++k) Bg[k] = egb[k];
#pragma unroll
    for (int k = 0; k < 18; ++k) Wc[k] = ecw[k];
#pragma unroll
    for (int k = 0; k < 3;  ++k) Cb[k] = ecb[k];

    int p = 0;
    // ---------------- encoder (global-free loop) ----------------
    for (int t = 0; t < TT; ++t) {
        const float* row = s_big + t * 361;
        float o_own=0.f, xa=0.f, xb=0.f;
        float h0a=0.f,h0b=0.f,h1a=0.f,h1b=0.f,h2a=0.f,h2b=0.f;
        if (act) {
            o_own = row[n]; xa = row[c1]; xb = row[c2];
            h0a = s_h[p][0][c1]; h0b = s_h[p][0][c2];
            h1a = s_h[p][1][c1]; h1b = s_h[p][1][c2];
            h2a = s_h[p][2][c1]; h2b = s_h[p][2][c2];
        }
        const int q = p ^ 1;
        // layer 0
        dc_layer(o_own, xa, xb, hreg[0], h0a, h0b, v, vv, c1, c2, act, n,
                 Wg, Bg[0], Bg[1], Wc, Cb[0], s_rh);
        if (act) { s_h[q][0][n] = hreg[0]; s_o[n] = hreg[0]; }
        __syncthreads();
        // layer 1
        float oa = 0.f, ob = 0.f;
        if (act) { oa = s_o[c1]; ob = s_o[c2]; }
        dc_layer(hreg[0], oa, ob, hreg[1], h1a, h1b, v, vv, c1, c2, act, n,
                 Wg + 12, Bg[2], Bg[3], Wc + 6, Cb[1], s_rh);
        if (act) { s_h[q][1][n] = hreg[1]; s_o[n] = hreg[1]; }
        __syncthreads();
        // layer 2
        if (act) { oa = s_o[c1]; ob = s_o[c2]; }
        dc_layer(hreg[1], oa, ob, hreg[2], h2a, h2b, v, vv, c1, c2, act, n,
                 Wg + 24, Bg[4], Bg[5], Wc + 12, Cb[2], s_rh);
        if (act) s_h[q][2][n] = hreg[2];
        __syncthreads();
        p = q;
    }

    // ---- decoder weights -> registers ----
#pragma unroll
    for (int k = 0; k < 36; ++k) Wg[k] = dgw[k];
#pragma unroll
    for (int k = 0; k < 6;  ++k) Bg[k] = dgb[k];
#pragma unroll
    for (int k = 0; k < 18; ++k) Wc[k] = dcw[k];
#pragma unroll
    for (int k = 0; k < 3;  ++k) Cb[k] = dcb[k];

    // ---------------- decoder (global-free loop; feedback via s_big) --------
    float dinp = 0.f;
    for (int t = 0; t < TT; ++t) {
        float xa=0.f, xb=0.f;
        float h0a=0.f,h0b=0.f,h1a=0.f,h1b=0.f,h2a=0.f,h2b=0.f;
        if (act) {
            if (t > 0) {   // prev-step proj at chain nodes (t=0: zeros)
                const float* prow = s_big + (t - 1) * 361;
                xa = prow[c1]; xb = prow[c2];
            }
            h0a = s_h[p][0][c1]; h0b = s_h[p][0][c2];
            h1a = s_h[p][1][c1]; h1b = s_h[p][1][c2];
            h2a = s_h[p][2][c1]; h2b = s_h[p][2][c2];
        }
        const int q = p ^ 1;
        dc_layer(dinp, xa, xb, hreg[0], h0a, h0b, v, vv, c1, c2, act, n,
                 Wg, Bg[0], Bg[1], Wc, Cb[0], s_rh);
        if (act) { s_h[q][0][n] = hreg[0]; s_o[n] = hreg[0]; }
        __syncthreads();
        float oa = 0.f, ob = 0.f;
        if (act) { oa = s_o[c1]; ob = s_o[c2]; }
        dc_layer(hreg[0], oa, ob, hreg[1], h1a, h1b, v, vv, c1, c2, act, n,
                 Wg + 12, Bg[2], Bg[3], Wc + 6, Cb[1], s_rh);
        if (act) { s_h[q][1][n] = hreg[1]; s_o[n] = hreg[1]; }
        __syncthreads();
        if (act) { oa = s_o[c1]; ob = s_o[c2]; }
        dc_layer(hreg[1], oa, ob, hreg[2], h2a, h2b, v, vv, c1, c2, act, n,
                 Wg + 24, Bg[4], Bg[5], Wc + 12, Cb[2], s_rh);
        float proj = hreg[2] * projw + projb;
        if (act) {
            s_h[q][2][n] = hreg[2];
            s_big[t * 361 + n] = proj;      // stage feedback + output in LDS
        }
        __syncthreads();
        dinp = proj; p = q;
    }

    // ---- coalesced LDS -> global writeout (covered by loop-final barrier) --
    for (int e = threadIdx.x; e < NNODE * TT; e += 384) {
        const int nn = e >> 6, t2 = e & 63;
        outp[((size_t)b * NNODE + nn) * TT + t2] = s_big[t2 * 361 + nn];
    }
}

// ---------------- host launcher ---------------------------------------------
extern "C" void kernel_launch(void* const* d_in, const int* in_sizes, int n_in,
                              void* d_out, int out_size, void* d_ws, size_t ws_size,
                              hipStream_t stream)
{
    (void)in_sizes; (void)n_in; (void)out_size; (void)ws_size;
    const float* full_seq = (const float*)d_in[0];   // (M,64,8)
    const float* rec_seq  = (const float*)d_in[1];   // (32,360,64)
    const float* temp     = (const float*)d_in[3];
    const float* g0wih    = (const float*)d_in[4];
    const float* g0whh    = (const float*)d_in[5];
    const float* g0bih    = (const float*)d_in[6];
    const float* g0bhh    = (const float*)d_in[7];
    const float* gwih     = (const float*)d_in[8];   // (3,2,24,16)
    const float* gwhh     = (const float*)d_in[9];   // (3,2,24,8)
    const float* gbih     = (const float*)d_in[10];
    const float* gbhh     = (const float*)d_in[11];
    const float* l1w      = (const float*)d_in[12];
    const float* l1b      = (const float*)d_in[13];
    const float* l2w      = (const float*)d_in[14];
    const float* l2b      = (const float*)d_in[15];
    const float* enc_gw   = (const float*)d_in[16];
    const float* enc_gb   = (const float*)d_in[17];
    const float* enc_cw   = (const float*)d_in[18];
    const float* enc_cb   = (const float*)d_in[19];
    const float* dec_gw   = (const float*)d_in[20];
    const float* dec_gb   = (const float*)d_in[21];
    const float* dec_cw   = (const float*)d_in[22];
    const float* dec_cb   = (const float*)d_in[23];
    const float* proj_w   = (const float*)d_in[24];
    const float* proj_b   = (const float*)d_in[25];
    float* outp = (float*)d_out;

    // ws: small-first; bufA+bufB ping-pong = 94.85 MB total (proven size)
    float* ws   = (float*)d_ws;
    float* feat = ws;                                     // (M,8)
    float* vbuf = feat + (size_t)M_SEQ * 8;               // (M,)
    int*   cbuf = (int*)(vbuf + M_SEQ);                   // (M,)
    float* bufA = (float*)(cbuf + M_SEQ);                 // (M,64,16)
    float* bufB = bufA + (size_t)M_SEQ * TT * 16;         // (M,64,16)

    const int ggru = (M_SEQ * 2 * 8) / 256;   // 720 blocks
    gru_fused<8,false><<<ggru, 256, 0, stream>>>(full_seq, g0wih, g0whh, g0bih, g0bhh, bufA);
    gru_fused<16,false><<<ggru, 256, 0, stream>>>(bufA, gwih + 0 * 768, gwhh + 0 * 384,
                                                  gbih + 0 * 48, gbhh + 0 * 48, bufB);
    gru_fused<16,false><<<ggru, 256, 0, stream>>>(bufB, gwih + 1 * 768, gwhh + 1 * 384,
                                                  gbih + 1 * 48, gbhh + 1 * 48, bufA);
    gru_fused<16,true><<<ggru, 256, 0, stream>>>(bufA, gwih + 2 * 768, gwhh + 2 * 384,
                                                 gbih + 2 * 48, gbhh + 2 * 48, bufB);
    feat_kernel<<<M_SEQ / 256, 256, 0, stream>>>(bufB, l1w, l1b, l2w, l2b, feat);
    adj_kernel<<<(NB * NNODE) / 4, 256, 0, stream>>>(feat, temp, cbuf, vbuf);
    decode_kernel<<<NB, 384, 0, stream>>>(rec_seq, cbuf, vbuf,
                                          enc_gw, enc_gb, enc_cw, enc_cb,
                                          dec_gw, dec_gb, dec_cw, dec_cb,
                                          proj_w, proj_b, outp);
}

// Round 5
// 525.590 us; speedup vs baseline: 1.1290x; 1.0413x over previous
//
#include <hip/hip_runtime.h>
#include <math.h>

#define M_SEQ 11520   // B*N
#define NNODE 360
#define NB    32
#define TT    64

// adj path: libm-accurate — gumbel/argmax pipeline bit-identical to proven state.
// GRU + decode: fast hardware exp (R12: absmax bit-unchanged).
__device__ __forceinline__ float fsigd(float x)  { return 1.0f / (1.0f + __expf(-x)); }
__device__ __forceinline__ float ftanhd(float x) { return 1.0f - 2.0f / (__expf(2.0f * x) + 1.0f); }

// Relaxed workgroup barrier: LDS-ordering only (lgkmcnt), no vmcnt(0) drain.
// Safe here because all global ops in the decode loops are thread-private.
__device__ __forceinline__ void lds_barrier()
{
    asm volatile("s_waitcnt lgkmcnt(0)" ::: "memory");
    __builtin_amdgcn_sched_barrier(0);
    __builtin_amdgcn_s_barrier();
    __builtin_amdgcn_sched_barrier(0);
}

// ---------------- JAX threefry2x32, key=(0,42), partitionable, bits=y0^y1 ----
__device__ __forceinline__ unsigned rotl32(unsigned x, int n) { return (x << n) | (x >> (32 - n)); }

__device__ __forceinline__ void tf2x32(unsigned& x0, unsigned& x1)
{
    const unsigned k0 = 0u, k1 = 42u, k2 = 0u ^ 42u ^ 0x1BD11BDAu;
    x0 += k0; x1 += k1;
#define R4(a,b,c,d) \
    x0 += x1; x1 = rotl32(x1,a); x1 ^= x0; \
    x0 += x1; x1 = rotl32(x1,b); x1 ^= x0; \
    x0 += x1; x1 = rotl32(x1,c); x1 ^= x0; \
    x0 += x1; x1 = rotl32(x1,d); x1 ^= x0;
    R4(13,15,26,6)   x0 += k1; x1 += k2 + 1u;
    R4(17,29,16,24)  x0 += k2; x1 += k0 + 2u;
    R4(13,15,26,6)   x0 += k0; x1 += k1 + 3u;
    R4(17,29,16,24)  x0 += k1; x1 += k2 + 4u;
    R4(13,15,26,6)   x0 += k2; x1 += k0 + 5u;
#undef R4
}

__device__ __forceinline__ float jax_uniform(unsigned idx)
{
    unsigned x0 = 0u, x1 = idx;
    tf2x32(x0, x1);
    unsigned bits = x0 ^ x1;          // VERIFIED R5
    return __uint_as_float((bits >> 9) | 0x3f800000u) - 1.0f;
}

// broadcast within aligned 8-lane group via static-pattern ds_swizzle.
template<int K>
__device__ __forceinline__ void swz_fma(float h, const float* w0, const float* w1,
                                        const float* w2, float& g0, float& g1, float& g2)
{
    float hk = __int_as_float(
        __builtin_amdgcn_ds_swizzle(__float_as_int(h), (K << 5) | 0x18));
    g0 += hk * w0[K];
    g1 += hk * w1[K];
    g2 += hk * w2[K];
    if constexpr (K < 7)
        swz_fma<K + 1>(h, w0, w1, w2, g0, g1, g2);
}

// ---------------- GRU helpers (h-independent x-path separated) --------------
template<int I>
__device__ __forceinline__ void ldx(float* __restrict__ xv, const float* __restrict__ p)
{
    const float4* p4 = reinterpret_cast<const float4*>(p);
#pragma unroll
    for (int q = 0; q < I / 4; ++q) {
        float4 f = p4[q];
        xv[4*q] = f.x; xv[4*q+1] = f.y; xv[4*q+2] = f.z; xv[4*q+3] = f.w;
    }
}

template<int I>
__device__ __forceinline__ void xgates(const float* __restrict__ xv,
    const float* wx0, const float* wx1, const float* wx2,
    float bx0, float bx1, float bx2, float& xr, float& xz, float& xn)
{
    xr = bx0; xz = bx1; xn = bx2;   // same accumulation order as R12 -> bit-identical
#pragma unroll
    for (int k = 0; k < I; ++k) {
        xr += xv[k] * wx0[k];
        xz += xv[k] * wx1[k];
        xn += xv[k] * wx2[k];
    }
}

__device__ __forceinline__ float hstep(float h, float xr, float xz, float xn,
    const float* w0, const float* w1, const float* w2,
    float bh0, float bh1, float bh2)
{
    float gh0 = bh0, gh1 = bh1, gh2 = bh2;
    swz_fma<0>(h, w0, w1, w2, gh0, gh1, gh2);
    float r  = fsigd(xr + gh0);
    float z  = fsigd(xz + gh1);
    float nn = ftanhd(xn + r * gh2);
    return (1.f - z) * nn + z * h;
}

// ---------------- fused bidirectional GRU layer, 2-deep x pipeline ----------
// LASTONLY: final layer — only the t=TT-1 output slot is ever consumed
// (fwd: its last h, written at t1==TT-1; bwd: its first h, written at t0==TT-1).
template<int I, bool LASTONLY>
__global__ __launch_bounds__(256) void gru_fused(
    const float* __restrict__ x,    // (M,64,I)
    const float* __restrict__ wih,  // (2,24,I)
    const float* __restrict__ whh,  // (2,24,8)
    const float* __restrict__ bih,  // (2,24)
    const float* __restrict__ bhh,  // (2,24)
    float* __restrict__ out)        // (M,64,16), dir writes its 8-half
{
    const int tid = blockIdx.x * 256 + threadIdx.x;
    const int j   = tid & 7;
    const int md  = tid >> 3;
    if (md >= M_SEQ * 2) return;
    const int m = md >> 1, dir = md & 1;

    float wx0[I], wx1[I], wx2[I];
    const float* WI = wih + dir * 24 * I;
#pragma unroll
    for (int k = 0; k < I; ++k) {
        wx0[k] = WI[j * I + k];
        wx1[k] = WI[(8 + j) * I + k];
        wx2[k] = WI[(16 + j) * I + k];
    }
    float w0[8], w1[8], w2[8];
    const float* WH = whh + dir * 192;
#pragma unroll
    for (int k = 0; k < 8; ++k) {
        w0[k] = WH[j * 8 + k];
        w1[k] = WH[(8 + j) * 8 + k];
        w2[k] = WH[(16 + j) * 8 + k];
    }
    const float bx0 = bih[dir*24 + j], bx1 = bih[dir*24 + 8 + j], bx2 = bih[dir*24 + 16 + j];
    const float bh0 = bhh[dir*24 + j], bh1 = bhh[dir*24 + 8 + j], bh2 = bhh[dir*24 + 16 + j];

    const float* xm = x + (size_t)m * TT * I;
    float* om = out + (size_t)m * TT * 16 + dir * 8 + j;

    const int tstep = dir ? -1 : 1;
    const int tbase = dir ? TT - 1 : 0;

    float h = 0.f;
    float xva[I], xvb[I];
    ldx<I>(xva, xm + (tbase) * I);                 // t(0)
    ldx<I>(xvb, xm + (tbase + tstep) * I);         // t(1)
    float cr, cz, cn;
    xgates<I>(xva, wx0, wx1, wx2, bx0, bx1, bx2, cr, cz, cn);   // gates(t(0))

    for (int tt = 0; tt < TT; tt += 2) {
        const int t0 = tbase + tstep * tt;
        const int t1 = t0 + tstep;
        // prefetch t(tt+2) into the slot whose data is already in c-gates
        if (tt + 2 < TT) ldx<I>(xva, xm + (t0 + 2 * tstep) * I);
        // gates(t(tt+1)) — h-independent, overlaps the recurrence stalls
        float nr, nz, nn;
        xgates<I>(xvb, wx0, wx1, wx2, bx0, bx1, bx2, nr, nz, nn);
        h = hstep(h, cr, cz, cn, w0, w1, w2, bh0, bh1, bh2);
        if (!LASTONLY || t0 == TT - 1) om[t0 * 16] = h;
        // prefetch t(tt+3); xvb's content was consumed into n-gates above
        if (tt + 3 < TT) ldx<I>(xvb, xm + (t0 + 3 * tstep) * I);
        h = hstep(h, nr, nz, nn, w0, w1, w2, bh0, bh1, bh2);
        if (!LASTONLY || t1 == TT - 1) om[t1 * 16] = h;
        // gates(t(tt+2)) from xva — placed last: max load->use distance
        xgates<I>(xva, wx0, wx1, wx2, bx0, bx1, bx2, cr, cz, cn);
    }
}

// ---------------- feat MLP (pure FMA) ---------------------------------------
__global__ void feat_kernel(const float* __restrict__ gout,
                            const float* __restrict__ l1w, const float* __restrict__ l1b,
                            const float* __restrict__ l2w, const float* __restrict__ l2b,
                            float* __restrict__ feat)
{
    int m = blockIdx.x * blockDim.x + threadIdx.x;
    if (m >= M_SEQ) return;
    const float* xp = gout + (size_t)m * TT * 16 + (TT - 1) * 16;
    float xv[16];
#pragma unroll
    for (int i = 0; i < 16; ++i) xv[i] = xp[i];
    float h1[8];
#pragma unroll
    for (int o = 0; o < 8; ++o) {
        float a = 0.f;
#pragma unroll
        for (int f = 0; f < 16; ++f) a += xv[f] * l1w[o * 16 + f];
        a += l1b[o];
        h1[o] = (a >= 0.f) ? a : 0.2f * a;
    }
#pragma unroll
    for (int o = 0; o < 8; ++o) {
        float a = 0.f;
#pragma unroll
        for (int f = 0; f < 8; ++f) a += h1[f] * l2w[o * 8 + f];
        feat[(size_t)m * 8 + o] = a + l2b[o];
    }
}

// ---------------- adjacency (libm — bit-identical to proven state) ----------
__global__ void adj_kernel(const float* __restrict__ feat,
                           const float* __restrict__ tptr,
                           int* __restrict__ colp, float* __restrict__ vp)
{
    const int gw   = (blockIdx.x * blockDim.x + threadIdx.x) >> 6;
    const int lane = threadIdx.x & 63;
    if (gw >= NB * NNODE) return;
    const int b = gw / NNODE;
    const int n = gw - b * NNODE;
    const float T = tptr[0];
    const float* fb = feat + (size_t)b * NNODE * 8;
    float fn[8];
#pragma unroll
    for (int k = 0; k < 8; ++k) fn[k] = fb[(size_t)n * 8 + k];

    float sv[6];
    float mval = -3.0e38f; int midx = 1 << 30;
#pragma unroll
    for (int s = 0; s < 6; ++s) {
        int p = s * 64 + lane;
        float xs = -3.0e38f;
        if (p < NNODE) {
            const float* fp = fb + (size_t)p * 8;
            float d = 0.f;
#pragma unroll
            for (int k = 0; k < 8; ++k) d += fn[k] * fp[k];
            unsigned idx = (unsigned)gw * 360u + (unsigned)p;
            float u   = jax_uniform(idx);
            float gum = -logf(-logf(u + 1e-10f) + 1e-10f);
            xs = (d + gum) / T;
            if (xs > mval) { mval = xs; midx = p; }
        }
        sv[s] = xs;
    }
    for (int off = 32; off > 0; off >>= 1) {   // ties -> smaller index
        float ov = __shfl_xor(mval, off);
        int   oi = __shfl_xor(midx, off);
        if (ov > mval || (ov == mval && oi < midx)) { mval = ov; midx = oi; }
    }
    float ssum = 0.f;
#pragma unroll
    for (int s = 0; s < 6; ++s) {
        int p = s * 64 + lane;
        if (p < NNODE) ssum += expf(sv[s] - mval);
    }
    for (int off = 32; off > 0; off >>= 1) ssum += __shfl_xor(ssum, off);
    if (lane == 0) {
        float ys = 1.0f / ssum;
        float v  = ys + (1.0f - ys);
        if (midx == n) v = 0.0f;
        colp[gw] = midx;
        vp[gw]   = v;
    }
}

// ---------------- DCGRU layer: R2-proven arithmetic --------------------------
// Expressions and evaluation order IDENTICAL to R2 -> bit-identical results.
// rh gathers issue before u is computed, so u's VALU hides under LDS latency.
// Barriers are lgkmcnt-only (lds_barrier): no vmcnt(0) drain of the in-flight
// thread-private global ops (rec prefetch / outp store).
__device__ __forceinline__ void dc_layer(
    float o_own, float oa, float ob,          // layer input at n, c1, c2
    float& hn, float ha, float hb,            // layer state at n (updated), c1, c2
    float v, float vv, int c1, int c2, bool act, int n,
    const float* __restrict__ W, float bgr, float bgu,
    const float* __restrict__ C, float cb,
    float* __restrict__ s_rh)
{
    float f1 = v * oa, f2 = vv * ob - o_own;
    float f4 = v * ha, f5 = vv * hb - hn;
    float r  = fsigd(o_own*W[0] + f1*W[2] + f2*W[4] + hn*W[6] + f4*W[8] + f5*W[10] + bgr);
    float rh = r * hn;
    if (act) s_rh[n] = rh;
    lds_barrier();
    // issue gathers first, then compute u (independent of r) under the latency
    float rha = s_rh[c1], rhb = s_rh[c2];
    float u  = fsigd(o_own*W[1] + f1*W[3] + f2*W[5] + hn*W[7] + f4*W[9] + f5*W[11] + bgu);
    float cnd = ftanhd(o_own*C[0] + f1*C[1] + f2*C[2] + rh*C[3]
                       + (v*rha)*C[4] + (vv*rhb - rh)*C[5] + cb);
    hn = u * hn + (1.f - u) * cnd;
}

// decode R5: exact R2 structure (proven 184.6 µs) with relaxed barriers.
//  - parity double-buffered s_h / s_x: previous-step state is read-only, so
//    all 8 cross-node gathers for the whole step issue together at step top
//  - all weights in registers/SGPRs (no LDS weight re-reads on the chain)
__global__ __launch_bounds__(384, 1) void decode_kernel(
    const float* __restrict__ rec,   // (B, N, T)
    const int*   __restrict__ colp, const float* __restrict__ vp,
    const float* __restrict__ egw, const float* __restrict__ egb,
    const float* __restrict__ ecw, const float* __restrict__ ecb,
    const float* __restrict__ dgw, const float* __restrict__ dgb,
    const float* __restrict__ dcw, const float* __restrict__ dcb,
    const float* __restrict__ pw,  const float* __restrict__ pb,
    float* __restrict__ outp)        // (B, N, T)
{
    __shared__ float s_h[2][3][NNODE];   // [parity][layer][node], 4B stride
    __shared__ float s_x[2][NNODE];      // [parity][node] layer-0 input staging
    __shared__ float s_o[NNODE];         // intra-step layer output exchange
    __shared__ float s_rh[NNODE];
    __shared__ float s_v[NNODE];
    __shared__ int   s_c[NNODE];

    const int b = blockIdx.x;
    const int n = threadIdx.x;
    const bool act = n < NNODE;

    float inp0 = 0.f;
    if (act) {
        s_c[n] = colp[b * NNODE + n];
        s_v[n] = vp[b * NNODE + n];
        inp0   = rec[((size_t)b * NNODE + n) * TT + 0];
        s_h[0][0][n] = 0.f; s_h[0][1][n] = 0.f; s_h[0][2][n] = 0.f;
        s_x[0][n] = inp0;
    }
    __syncthreads();   // init barrier: full drain (one-time)

    int c1 = 0, c2 = 0;
    float v = 0.f, vv = 0.f;
    if (act) {
        c1 = s_c[n];
        c2 = s_c[c1];
        v  = s_v[n];
        vv = 2.f * v * s_v[c1];
    }
    const float projw = pw[0], projb = pb[0];
    float hreg[3] = {0.f, 0.f, 0.f};

    // ---- encoder weights -> registers (uniform loads -> SGPRs) ----
    float Wg[36], Bg[6], Wc[18], Cb[3];
#pragma unroll
    for (int k = 0; k < 36; ++k) Wg[k] = egw[k];
#pragma unroll
    for (int k = 0; k < 6;  ++k) Bg[k] = egb[k];
#pragma unroll
    for (int k = 0; k < 18; ++k) Wc[k] = ecw[k];
#pragma unroll
    for (int k = 0; k < 3;  ++k) Cb[k] = ecb[k];

    float o_own = inp0;
    int p = 0;
    // ---------------- encoder ----------------
    for (int t = 0; t < TT; ++t) {
        float nx = (act && t + 1 < TT) ? rec[((size_t)b * NNODE + n) * TT + t + 1] : 0.f;
        // all previous-step-state gathers issue together (parity p read-only)
        float xa  = s_x[p][c1],    xb  = s_x[p][c2];
        float h0a = s_h[p][0][c1], h0b = s_h[p][0][c2];
        float h1a = s_h[p][1][c1], h1b = s_h[p][1][c2];
        float h2a = s_h[p][2][c1], h2b = s_h[p][2][c2];
        const int q = p ^ 1;
        // layer 0
        dc_layer(o_own, xa, xb, hreg[0], h0a, h0b, v, vv, c1, c2, act, n,
                 Wg, Bg[0], Bg[1], Wc, Cb[0], s_rh);
        if (act) { s_h[q][0][n] = hreg[0]; s_o[n] = hreg[0]; }
        lds_barrier();
        // layer 1
        float oa = s_o[c1], ob = s_o[c2];
        dc_layer(hreg[0], oa, ob, hreg[1], h1a, h1b, v, vv, c1, c2, act, n,
                 Wg + 12, Bg[2], Bg[3], Wc + 6, Cb[1], s_rh);
        if (act) { s_h[q][1][n] = hreg[1]; s_o[n] = hreg[1]; }
        lds_barrier();
        // layer 2
        oa = s_o[c1]; ob = s_o[c2];
        dc_layer(hreg[1], oa, ob, hreg[2], h2a, h2b, v, vv, c1, c2, act, n,
                 Wg + 24, Bg[4], Bg[5], Wc + 12, Cb[2], s_rh);
        if (act) { s_h[q][2][n] = hreg[2]; s_x[q][n] = nx; }  // stage next input
        lds_barrier();
        o_own = nx; p = q;
    }
    // 64 steps -> p back to 0; s_x[0][n] == 0 == first decoder input.

    // ---- decoder weights -> registers ----
#pragma unroll
    for (int k = 0; k < 36; ++k) Wg[k] = dgw[k];
#pragma unroll
    for (int k = 0; k < 6;  ++k) Bg[k] = dgb[k];
#pragma unroll
    for (int k = 0; k < 18; ++k) Wc[k] = dcw[k];
#pragma unroll
    for (int k = 0; k < 3;  ++k) Cb[k] = dcb[k];

    // ---------------- decoder ----------------
    float dinp = 0.f;
    for (int t = 0; t < TT; ++t) {
        float xa  = s_x[p][c1],    xb  = s_x[p][c2];
        float h0a = s_h[p][0][c1], h0b = s_h[p][0][c2];
        float h1a = s_h[p][1][c1], h1b = s_h[p][1][c2];
        float h2a = s_h[p][2][c1], h2b = s_h[p][2][c2];
        const int q = p ^ 1;
        dc_layer(dinp, xa, xb, hreg[0], h0a, h0b, v, vv, c1, c2, act, n,
                 Wg, Bg[0], Bg[1], Wc, Cb[0], s_rh);
        if (act) { s_h[q][0][n] = hreg[0]; s_o[n] = hreg[0]; }
        lds_barrier();
        float oa = s_o[c1], ob = s_o[c2];
        dc_layer(hreg[0], oa, ob, hreg[1], h1a, h1b, v, vv, c1, c2, act, n,
                 Wg + 12, Bg[2], Bg[3], Wc + 6, Cb[1], s_rh);
        if (act) { s_h[q][1][n] = hreg[1]; s_o[n] = hreg[1]; }
        lds_barrier();
        oa = s_o[c1]; ob = s_o[c2];
        dc_layer(hreg[1], oa, ob, hreg[2], h2a, h2b, v, vv, c1, c2, act, n,
                 Wg + 24, Bg[4], Bg[5], Wc + 12, Cb[2], s_rh);
        float proj = hreg[2] * projw + projb;
        if (act) {
            s_h[q][2][n] = hreg[2];
            s_x[q][n] = proj;                    // stage next decoder input
            outp[((size_t)b * NNODE + n) * TT + t] = proj;
        }
        lds_barrier();
        dinp = proj; p = q;
    }
}

// ---------------- host launcher ---------------------------------------------
extern "C" void kernel_launch(void* const* d_in, const int* in_sizes, int n_in,
                              void* d_out, int out_size, void* d_ws, size_t ws_size,
                              hipStream_t stream)
{
    (void)in_sizes; (void)n_in; (void)out_size; (void)ws_size;
    const float* full_seq = (const float*)d_in[0];   // (M,64,8)
    const float* rec_seq  = (const float*)d_in[1];   // (32,360,64)
    const float* temp     = (const float*)d_in[3];
    const float* g0wih    = (const float*)d_in[4];
    const float* g0whh    = (const float*)d_in[5];
    const float* g0bih    = (const float*)d_in[6];
    const float* g0bhh    = (const float*)d_in[7];
    const float* gwih     = (const float*)d_in[8];   // (3,2,24,16)
    const float* gwhh     = (const float*)d_in[9];   // (3,2,24,8)
    const float* gbih     = (const float*)d_in[10];
    const float* gbhh     = (const float*)d_in[11];
    const float* l1w      = (const float*)d_in[12];
    const float* l1b      = (const float*)d_in[13];
    const float* l2w      = (const float*)d_in[14];
    const float* l2b      = (const float*)d_in[15];
    const float* enc_gw   = (const float*)d_in[16];
    const float* enc_gb   = (const float*)d_in[17];
    const float* enc_cw   = (const float*)d_in[18];
    const float* enc_cb   = (const float*)d_in[19];
    const float* dec_gw   = (const float*)d_in[20];
    const float* dec_gb   = (const float*)d_in[21];
    const float* dec_cw   = (const float*)d_in[22];
    const float* dec_cb   = (const float*)d_in[23];
    const float* proj_w   = (const float*)d_in[24];
    const float* proj_b   = (const float*)d_in[25];
    float* outp = (float*)d_out;

    // ws: small-first; bufA+bufB ping-pong = 94.85 MB total (proven size)
    float* ws   = (float*)d_ws;
    float* feat = ws;                                     // (M,8)
    float* vbuf = feat + (size_t)M_SEQ * 8;               // (M,)
    int*   cbuf = (int*)(vbuf + M_SEQ);                   // (M,)
    float* bufA = (float*)(cbuf + M_SEQ);                 // (M,64,16)
    float* bufB = bufA + (size_t)M_SEQ * TT * 16;         // (M,64,16)

    const int ggru = (M_SEQ * 2 * 8) / 256;   // 720 blocks
    gru_fused<8,false><<<ggru, 256, 0, stream>>>(full_seq, g0wih, g0whh, g0bih, g0bhh, bufA);
    gru_fused<16,false><<<ggru, 256, 0, stream>>>(bufA, gwih + 0 * 768, gwhh + 0 * 384,
                                                  gbih + 0 * 48, gbhh + 0 * 48, bufB);
    gru_fused<16,false><<<ggru, 256, 0, stream>>>(bufB, gwih + 1 * 768, gwhh + 1 * 384,
                                                  gbih + 1 * 48, gbhh + 1 * 48, bufA);
    gru_fused<16,true><<<ggru, 256, 0, stream>>>(bufA, gwih + 2 * 768, gwhh + 2 * 384,
                                                 gbih + 2 * 48, gbhh + 2 * 48, bufB);
    feat_kernel<<<M_SEQ / 256, 256, 0, stream>>>(bufB, l1w, l1b, l2w, l2b, feat);
    adj_kernel<<<(NB * NNODE) / 4, 256, 0, stream>>>(feat, temp, cbuf, vbuf);
    decode_kernel<<<NB, 384, 0, stream>>>(rec_seq, cbuf, vbuf,
                                          enc_gw, enc_gb, enc_cw, enc_cb,
                                          dec_gw, dec_gb, dec_cw, dec_cb,
                                          proj_w, proj_b, outp);
}

// Round 6
// 512.699 us; speedup vs baseline: 1.1574x; 1.0251x over previous
//
#include <hip/hip_runtime.h>
#include <math.h>

#define M_SEQ 11520   // B*N
#define NNODE 360
#define NB    32
#define TT    64

// adj path: libm-accurate — gumbel/argmax pipeline bit-identical to proven state.
// GRU + decode: fast hardware exp (R12: absmax bit-unchanged).
__device__ __forceinline__ float fsigd(float x)  { return 1.0f / (1.0f + __expf(-x)); }
__device__ __forceinline__ float ftanhd(float x) { return 1.0f - 2.0f / (__expf(2.0f * x) + 1.0f); }

// Relaxed workgroup barrier: LDS-ordering only (lgkmcnt), no vmcnt(0) drain.
// Safe: all global ops in the decode loops are thread-private (R5-proven).
__device__ __forceinline__ void lds_barrier()
{
    asm volatile("s_waitcnt lgkmcnt(0)" ::: "memory");
    __builtin_amdgcn_sched_barrier(0);
    __builtin_amdgcn_s_barrier();
    __builtin_amdgcn_sched_barrier(0);
}

// ---------------- JAX threefry2x32, key=(0,42), partitionable, bits=y0^y1 ----
__device__ __forceinline__ unsigned rotl32(unsigned x, int n) { return (x << n) | (x >> (32 - n)); }

__device__ __forceinline__ void tf2x32(unsigned& x0, unsigned& x1)
{
    const unsigned k0 = 0u, k1 = 42u, k2 = 0u ^ 42u ^ 0x1BD11BDAu;
    x0 += k0; x1 += k1;
#define R4(a,b,c,d) \
    x0 += x1; x1 = rotl32(x1,a); x1 ^= x0; \
    x0 += x1; x1 = rotl32(x1,b); x1 ^= x0; \
    x0 += x1; x1 = rotl32(x1,c); x1 ^= x0; \
    x0 += x1; x1 = rotl32(x1,d); x1 ^= x0;
    R4(13,15,26,6)   x0 += k1; x1 += k2 + 1u;
    R4(17,29,16,24)  x0 += k2; x1 += k0 + 2u;
    R4(13,15,26,6)   x0 += k0; x1 += k1 + 3u;
    R4(17,29,16,24)  x0 += k1; x1 += k2 + 4u;
    R4(13,15,26,6)   x0 += k2; x1 += k0 + 5u;
#undef R4
}

__device__ __forceinline__ float jax_uniform(unsigned idx)
{
    unsigned x0 = 0u, x1 = idx;
    tf2x32(x0, x1);
    unsigned bits = x0 ^ x1;          // VERIFIED R5
    return __uint_as_float((bits >> 9) | 0x3f800000u) - 1.0f;
}

// broadcast within aligned 8-lane group via static-pattern ds_swizzle.
template<int K>
__device__ __forceinline__ void swz_fma(float h, const float* w0, const float* w1,
                                        const float* w2, float& g0, float& g1, float& g2)
{
    float hk = __int_as_float(
        __builtin_amdgcn_ds_swizzle(__float_as_int(h), (K << 5) | 0x18));
    g0 += hk * w0[K];
    g1 += hk * w1[K];
    g2 += hk * w2[K];
    if constexpr (K < 7)
        swz_fma<K + 1>(h, w0, w1, w2, g0, g1, g2);
}

// ---------------- GRU helpers (h-independent x-path separated) --------------
template<int I>
__device__ __forceinline__ void ldx(float* __restrict__ xv, const float* __restrict__ p)
{
    const float4* p4 = reinterpret_cast<const float4*>(p);
#pragma unroll
    for (int q = 0; q < I / 4; ++q) {
        float4 f = p4[q];
        xv[4*q] = f.x; xv[4*q+1] = f.y; xv[4*q+2] = f.z; xv[4*q+3] = f.w;
    }
}

template<int I>
__device__ __forceinline__ void xgates(const float* __restrict__ xv,
    const float* wx0, const float* wx1, const float* wx2,
    float bx0, float bx1, float bx2, float& xr, float& xz, float& xn)
{
    xr = bx0; xz = bx1; xn = bx2;   // same accumulation order as R12 -> bit-identical
#pragma unroll
    for (int k = 0; k < I; ++k) {
        xr += xv[k] * wx0[k];
        xz += xv[k] * wx1[k];
        xn += xv[k] * wx2[k];
    }
}

__device__ __forceinline__ float hstep(float h, float xr, float xz, float xn,
    const float* w0, const float* w1, const float* w2,
    float bh0, float bh1, float bh2)
{
    float gh0 = bh0, gh1 = bh1, gh2 = bh2;
    swz_fma<0>(h, w0, w1, w2, gh0, gh1, gh2);
    float r  = fsigd(xr + gh0);
    float z  = fsigd(xz + gh1);
    float nn = ftanhd(xn + r * gh2);
    return (1.f - z) * nn + z * h;
}

// ---------------- fused bidirectional GRU layer, 2-deep x pipeline ----------
// LASTONLY: final layer — only the t=TT-1 output slot is ever consumed.
template<int I, bool LASTONLY>
__global__ __launch_bounds__(256) void gru_fused(
    const float* __restrict__ x,    // (M,64,I)
    const float* __restrict__ wih,  // (2,24,I)
    const float* __restrict__ whh,  // (2,24,8)
    const float* __restrict__ bih,  // (2,24)
    const float* __restrict__ bhh,  // (2,24)
    float* __restrict__ out)        // (M,64,16), dir writes its 8-half
{
    const int tid = blockIdx.x * 256 + threadIdx.x;
    const int j   = tid & 7;
    const int md  = tid >> 3;
    if (md >= M_SEQ * 2) return;
    const int m = md >> 1, dir = md & 1;

    float wx0[I], wx1[I], wx2[I];
    const float* WI = wih + dir * 24 * I;
#pragma unroll
    for (int k = 0; k < I; ++k) {
        wx0[k] = WI[j * I + k];
        wx1[k] = WI[(8 + j) * I + k];
        wx2[k] = WI[(16 + j) * I + k];
    }
    float w0[8], w1[8], w2[8];
    const float* WH = whh + dir * 192;
#pragma unroll
    for (int k = 0; k < 8; ++k) {
        w0[k] = WH[j * 8 + k];
        w1[k] = WH[(8 + j) * 8 + k];
        w2[k] = WH[(16 + j) * 8 + k];
    }
    const float bx0 = bih[dir*24 + j], bx1 = bih[dir*24 + 8 + j], bx2 = bih[dir*24 + 16 + j];
    const float bh0 = bhh[dir*24 + j], bh1 = bhh[dir*24 + 8 + j], bh2 = bhh[dir*24 + 16 + j];

    const float* xm = x + (size_t)m * TT * I;
    float* om = out + (size_t)m * TT * 16 + dir * 8 + j;

    const int tstep = dir ? -1 : 1;
    const int tbase = dir ? TT - 1 : 0;

    float h = 0.f;
    float xva[I], xvb[I];
    ldx<I>(xva, xm + (tbase) * I);                 // t(0)
    ldx<I>(xvb, xm + (tbase + tstep) * I);         // t(1)
    float cr, cz, cn;
    xgates<I>(xva, wx0, wx1, wx2, bx0, bx1, bx2, cr, cz, cn);   // gates(t(0))

    for (int tt = 0; tt < TT; tt += 2) {
        const int t0 = tbase + tstep * tt;
        const int t1 = t0 + tstep;
        if (tt + 2 < TT) ldx<I>(xva, xm + (t0 + 2 * tstep) * I);
        float nr, nz, nn;
        xgates<I>(xvb, wx0, wx1, wx2, bx0, bx1, bx2, nr, nz, nn);
        h = hstep(h, cr, cz, cn, w0, w1, w2, bh0, bh1, bh2);
        if (!LASTONLY || t0 == TT - 1) om[t0 * 16] = h;
        if (tt + 3 < TT) ldx<I>(xvb, xm + (t0 + 3 * tstep) * I);
        h = hstep(h, nr, nz, nn, w0, w1, w2, bh0, bh1, bh2);
        if (!LASTONLY || t1 == TT - 1) om[t1 * 16] = h;
        xgates<I>(xva, wx0, wx1, wx2, bx0, bx1, bx2, cr, cz, cn);
    }
}

// ---------------- feat MLP (pure FMA) ---------------------------------------
__global__ void feat_kernel(const float* __restrict__ gout,
                            const float* __restrict__ l1w, const float* __restrict__ l1b,
                            const float* __restrict__ l2w, const float* __restrict__ l2b,
                            float* __restrict__ feat)
{
    int m = blockIdx.x * blockDim.x + threadIdx.x;
    if (m >= M_SEQ) return;
    const float* xp = gout + (size_t)m * TT * 16 + (TT - 1) * 16;
    float xv[16];
#pragma unroll
    for (int i = 0; i < 16; ++i) xv[i] = xp[i];
    float h1[8];
#pragma unroll
    for (int o = 0; o < 8; ++o) {
        float a = 0.f;
#pragma unroll
        for (int f = 0; f < 16; ++f) a += xv[f] * l1w[o * 16 + f];
        a += l1b[o];
        h1[o] = (a >= 0.f) ? a : 0.2f * a;
    }
#pragma unroll
    for (int o = 0; o < 8; ++o) {
        float a = 0.f;
#pragma unroll
        for (int f = 0; f < 8; ++f) a += h1[f] * l2w[o * 8 + f];
        feat[(size_t)m * 8 + o] = a + l2b[o];
    }
}

// ---------------- adjacency (libm — bit-identical to proven state) ----------
__global__ void adj_kernel(const float* __restrict__ feat,
                           const float* __restrict__ tptr,
                           int* __restrict__ colp, float* __restrict__ vp)
{
    const int gw   = (blockIdx.x * blockDim.x + threadIdx.x) >> 6;
    const int lane = threadIdx.x & 63;
    if (gw >= NB * NNODE) return;
    const int b = gw / NNODE;
    const int n = gw - b * NNODE;
    const float T = tptr[0];
    const float* fb = feat + (size_t)b * NNODE * 8;
    float fn[8];
#pragma unroll
    for (int k = 0; k < 8; ++k) fn[k] = fb[(size_t)n * 8 + k];

    float sv[6];
    float mval = -3.0e38f; int midx = 1 << 30;
#pragma unroll
    for (int s = 0; s < 6; ++s) {
        int p = s * 64 + lane;
        float xs = -3.0e38f;
        if (p < NNODE) {
            const float* fp = fb + (size_t)p * 8;
            float d = 0.f;
#pragma unroll
            for (int k = 0; k < 8; ++k) d += fn[k] * fp[k];
            unsigned idx = (unsigned)gw * 360u + (unsigned)p;
            float u   = jax_uniform(idx);
            float gum = -logf(-logf(u + 1e-10f) + 1e-10f);
            xs = (d + gum) / T;
            if (xs > mval) { mval = xs; midx = p; }
        }
        sv[s] = xs;
    }
    for (int off = 32; off > 0; off >>= 1) {   // ties -> smaller index
        float ov = __shfl_xor(mval, off);
        int   oi = __shfl_xor(midx, off);
        if (ov > mval || (ov == mval && oi < midx)) { mval = ov; midx = oi; }
    }
    float ssum = 0.f;
#pragma unroll
    for (int s = 0; s < 6; ++s) {
        int p = s * 64 + lane;
        if (p < NNODE) ssum += expf(sv[s] - mval);
    }
    for (int off = 32; off > 0; off >>= 1) ssum += __shfl_xor(ssum, off);
    if (lane == 0) {
        float ys = 1.0f / ssum;
        float v  = ys + (1.0f - ys);
        if (midx == n) v = 0.0f;
        colp[gw] = midx;
        vp[gw]   = v;
    }
}

// ---------------- DCGRU layer (decoder): R2-proven arithmetic ---------------
// comp is wave-uniform (group A); B-waves skip compute but share the barrier.
__device__ __forceinline__ void dc_layer(
    bool comp,
    float o_own, float oa, float ob,
    float& hn, float ha, float hb,
    float v, float vv, int c1, int c2, bool act, int n,
    const float* __restrict__ W, float bgr, float bgu,
    const float* __restrict__ C, float cb,
    float* __restrict__ s_rh)
{
    float f1 = 0.f, f2 = 0.f, f4 = 0.f, f5 = 0.f, rh = 0.f;
    if (comp) {
        f1 = v * oa; f2 = vv * ob - o_own;
        f4 = v * ha; f5 = vv * hb - hn;
        float r = fsigd(o_own*W[0] + f1*W[2] + f2*W[4] + hn*W[6] + f4*W[8] + f5*W[10] + bgr);
        rh = r * hn;
        if (act) s_rh[n] = rh;
    }
    lds_barrier();
    if (comp) {
        float rha = s_rh[c1], rhb = s_rh[c2];
        float u  = fsigd(o_own*W[1] + f1*W[3] + f2*W[5] + hn*W[7] + f4*W[9] + f5*W[11] + bgu);
        float cnd = ftanhd(o_own*C[0] + f1*C[1] + f2*C[2] + rh*C[3]
                           + (v*rha)*C[4] + (vv*rhb - rh)*C[5] + cb);
        hn = u * hn + (1.f - u) * cnd;
    }
}

// decode R6: 768 threads = 2 wave-groups.
// ENCODER: 2-stage software pipeline, 3 phases/slot, 2 timesteps in flight.
//   A (waves 0-5):  L0 (both phases) at tA=k, then L1 phase-1 (r,u,cpart).
//   B (waves 6-11): L1 phase-2 at tB=k-1 (consumes A's rh1/u1/cp1), then L2.
//   cpart = first 3 FMA terms of cnd's chain -> bit-identical continuation.
// DECODER: serial chain (no pipeline possible); R2 structure on A-waves,
//   B-waves uniform-skip compute, share barriers.
__global__ __launch_bounds__(768, 1) void decode_kernel(
    const float* __restrict__ rec,   // (B, N, T)
    const int*   __restrict__ colp, const float* __restrict__ vp,
    const float* __restrict__ egw, const float* __restrict__ egb,
    const float* __restrict__ ecw, const float* __restrict__ ecb,
    const float* __restrict__ dgw, const float* __restrict__ dgb,
    const float* __restrict__ dcw, const float* __restrict__ dcb,
    const float* __restrict__ pw,  const float* __restrict__ pb,
    float* __restrict__ outp)        // (B, N, T)
{
    __shared__ float s_h[2][3][NNODE];   // [parity][layer][node]
    __shared__ float s_xe[2][NNODE];     // [parity] L0 input row (enc) / s_x (dec)
    __shared__ float s_r1[2][NNODE];     // A->B handoff: rh1
    __shared__ float s_u1[2][NNODE];     //              u1
    __shared__ float s_c1[2][NNODE];     //              cpart1
    __shared__ float s_rh0[NNODE];       // L0 intra-slot rh exchange
    __shared__ float s_rh2[NNODE];       // L2 intra-slot rh exchange
    __shared__ float s_o[NNODE];         // decoder layer-output exchange
    __shared__ float s_rhd[NNODE];       // decoder rh exchange
    __shared__ float s_v[NNODE];
    __shared__ int   s_c[NNODE];

    const int  b    = blockIdx.x;
    const int  tid  = threadIdx.x;
    const bool isB  = tid >= 384;
    const bool isA  = !isB;
    const int  node = isB ? tid - 384 : tid;
    const bool actN = node < NNODE;

    const float* recb = rec + ((size_t)b * NNODE + node) * TT;

    float o_own = 0.f, xq1 = 0.f;
    if (isA && actN) {
        s_c[node] = colp[b * NNODE + node];
        s_v[node] = vp[b * NNODE + node];
        o_own = recb[0];
        xq1   = recb[1];
        s_xe[0][node] = o_own;
#pragma unroll
        for (int l = 0; l < 3; ++l) { s_h[0][l][node] = 0.f; s_h[1][l][node] = 0.f; }
    }
    __syncthreads();   // one-time full barrier

    int c1 = 0, c2 = 0;
    float v = 0.f, vv = 0.f;
    if (actN) {
        c1 = s_c[node];
        c2 = s_c[c1];
        v  = s_v[node];
        vv = 2.f * v * s_v[c1];
    }
    const float projw = pw[0], projb = pb[0];

    // ---- encoder weights -> registers ----
    float Wg[36], Bg[6], Wc[18], Cb[3];
#pragma unroll
    for (int k = 0; k < 36; ++k) Wg[k] = egw[k];
#pragma unroll
    for (int k = 0; k < 6;  ++k) Bg[k] = egb[k];
#pragma unroll
    for (int k = 0; k < 18; ++k) Wc[k] = ecw[k];
#pragma unroll
    for (int k = 0; k < 3;  ++k) Cb[k] = ecb[k];

    float h0r = 0.f, h1r = 0.f, h2r = 0.f;

    // ---------------- encoder: 65 slots x 3 phases ----------------
    for (int k = 0; k <= TT; ++k) {
        const int  pk = k & 1, qk = pk ^ 1;
        const bool aAct = isA && actN && (k < TT);
        const bool bAct = isB && actN && (k >= 1);
        float nx2 = 0.f;
        if (aAct && k + 2 < TT) nx2 = recb[k + 2];

        // ---------- phase 1: A = L0-ph1(tA) | B = L1-ph2(tB) ----------
        float fA1=0.f, fA2=0.f, fA4=0.f, fA5=0.f, rhA=0.f;
        if (isA) {
            float xa  = s_xe[pk][c1],   xb  = s_xe[pk][c2];
            float h0a = s_h[pk][0][c1], h0b = s_h[pk][0][c2];
            fA1 = v * xa;  fA2 = vv * xb - o_own;
            fA4 = v * h0a; fA5 = vv * h0b - h0r;
            float rA = fsigd(o_own*Wg[0] + fA1*Wg[2] + fA2*Wg[4] + h0r*Wg[6]
                             + fA4*Wg[8] + fA5*Wg[10] + Bg[0]);
            rhA = rA * h0r;
            if (aAct) s_rh0[node] = rhA;
        } else {
            float rh1o = s_r1[pk][node];
            float rh1a = s_r1[pk][c1], rh1b = s_r1[pk][c2];
            float u1v  = s_u1[pk][node], cp1v = s_c1[pk][node];
            float cnd1 = ftanhd(cp1v + rh1o*Wc[9] + (v*rh1a)*Wc[10]
                                + (vv*rh1b - rh1o)*Wc[11] + Cb[1]);
            if (bAct) { h1r = u1v * h1r + (1.f - u1v) * cnd1; s_h[qk][1][node] = h1r; }
        }
        lds_barrier();

        // ---------- phase 2: A = L0-ph2(tA) | B = L2-ph1(tB) ----------
        float fB1=0.f, fB2=0.f, fB4=0.f, fB5=0.f, rhB=0.f;
        if (isA) {
            float rh0a = s_rh0[c1], rh0b = s_rh0[c2];
            float uA = fsigd(o_own*Wg[1] + fA1*Wg[3] + fA2*Wg[5] + h0r*Wg[7]
                             + fA4*Wg[9] + fA5*Wg[11] + Bg[1]);
            float cndA = ftanhd(o_own*Wc[0] + fA1*Wc[1] + fA2*Wc[2] + rhA*Wc[3]
                                + (v*rh0a)*Wc[4] + (vv*rh0b - rhA)*Wc[5] + Cb[0]);
            if (aAct) {
                h0r = uA * h0r + (1.f - uA) * cndA;
                s_h[qk][0][node] = h0r;
                s_xe[qk][node]   = xq1;
            }
        } else {
            float o2a = s_h[qk][1][c1], o2b = s_h[qk][1][c2];
            float h2a = s_h[pk][2][c1], h2b = s_h[pk][2][c2];
            fB1 = v * o2a; fB2 = vv * o2b - h1r;
            fB4 = v * h2a; fB5 = vv * h2b - h2r;
            float rB = fsigd(h1r*Wg[24] + fB1*Wg[26] + fB2*Wg[28] + h2r*Wg[30]
                             + fB4*Wg[32] + fB5*Wg[34] + Bg[4]);
            rhB = rB * h2r;
            if (bAct) s_rh2[node] = rhB;
        }
        lds_barrier();

        // ---------- phase 3: A = L1-ph1(tA) | B = L2-ph2(tB) ----------
        if (isA) {
            float o1a = s_h[qk][0][c1], o1b = s_h[qk][0][c2];
            float h1own = s_h[qk][1][node];
            float h1a = s_h[qk][1][c1], h1b = s_h[qk][1][c2];
            float fC1 = v * o1a, fC2 = vv * o1b - h0r;
            float fC4 = v * h1a, fC5 = vv * h1b - h1own;
            float r1 = fsigd(h0r*Wg[12] + fC1*Wg[14] + fC2*Wg[16] + h1own*Wg[18]
                             + fC4*Wg[20] + fC5*Wg[22] + Bg[2]);
            float u1 = fsigd(h0r*Wg[13] + fC1*Wg[15] + fC2*Wg[17] + h1own*Wg[19]
                             + fC4*Wg[21] + fC5*Wg[23] + Bg[3]);
            float cp1 = h0r*Wc[6] + fC1*Wc[7] + fC2*Wc[8];
            if (aAct) { s_r1[qk][node] = r1 * h1own; s_u1[qk][node] = u1; s_c1[qk][node] = cp1; }
        } else {
            float rh2a = s_rh2[c1], rh2b = s_rh2[c2];
            float u2 = fsigd(h1r*Wg[25] + fB1*Wg[27] + fB2*Wg[29] + h2r*Wg[31]
                             + fB4*Wg[33] + fB5*Wg[35] + Bg[5]);
            float cnd2 = ftanhd(h1r*Wc[12] + fB1*Wc[13] + fB2*Wc[14] + rhB*Wc[15]
                                + (v*rh2a)*Wc[16] + (vv*rh2b - rhB)*Wc[17] + Cb[2]);
            if (bAct) { h2r = u2 * h2r + (1.f - u2) * cnd2; s_h[qk][2][node] = h2r; }
        }
        lds_barrier();
        if (isA) { o_own = xq1; xq1 = nx2; }
    }
    // finals: h0(63) in A regs & s_h[0][0]; h1(63) in s_h[1][1]; h2(63) in s_h[1][2].

    // ---- decoder init: normalize parity-0 state, zero first input ----
    if (tid < NNODE) {
        s_h[0][1][tid] = s_h[1][1][tid];
        s_h[0][2][tid] = s_h[1][2][tid];
        s_xe[0][tid]   = 0.f;
    }
    __syncthreads();

    const bool actd = (isA && actN);
    const int  nd   = actN ? node : 0;
    float hreg[3];
    hreg[0] = h0r;
    hreg[1] = s_h[0][1][nd];
    hreg[2] = s_h[0][2][nd];

    // ---- decoder weights -> registers ----
#pragma unroll
    for (int k = 0; k < 36; ++k) Wg[k] = dgw[k];
#pragma unroll
    for (int k = 0; k < 6;  ++k) Bg[k] = dgb[k];
#pragma unroll
    for (int k = 0; k < 18; ++k) Wc[k] = dcw[k];
#pragma unroll
    for (int k = 0; k < 3;  ++k) Cb[k] = dcb[k];

    // ---------------- decoder: R2 structure, A-waves compute ----------------
    float dinp = 0.f;
    int p = 0;
    for (int t = 0; t < TT; ++t) {
        float xa=0.f, xb=0.f;
        float h0a=0.f,h0b=0.f,h1a=0.f,h1b=0.f,h2a=0.f,h2b=0.f;
        if (isA) {
            xa  = s_xe[p][c1];     xb  = s_xe[p][c2];
            h0a = s_h[p][0][c1];   h0b = s_h[p][0][c2];
            h1a = s_h[p][1][c1];   h1b = s_h[p][1][c2];
            h2a = s_h[p][2][c1];   h2b = s_h[p][2][c2];
        }
        const int q = p ^ 1;
        dc_layer(isA, dinp, xa, xb, hreg[0], h0a, h0b, v, vv, c1, c2, actd, node,
                 Wg, Bg[0], Bg[1], Wc, Cb[0], s_rhd);
        if (actd) { s_h[q][0][node] = hreg[0]; s_o[node] = hreg[0]; }
        lds_barrier();
        float oa=0.f, ob=0.f;
        if (isA) { oa = s_o[c1]; ob = s_o[c2]; }
        dc_layer(isA, hreg[0], oa, ob, hreg[1], h1a, h1b, v, vv, c1, c2, actd, node,
                 Wg + 12, Bg[2], Bg[3], Wc + 6, Cb[1], s_rhd);
        if (actd) { s_h[q][1][node] = hreg[1]; s_o[node] = hreg[1]; }
        lds_barrier();
        if (isA) { oa = s_o[c1]; ob = s_o[c2]; }
        dc_layer(isA, hreg[1], oa, ob, hreg[2], h2a, h2b, v, vv, c1, c2, actd, node,
                 Wg + 24, Bg[4], Bg[5], Wc + 12, Cb[2], s_rhd);
        float proj = hreg[2] * projw + projb;
        if (actd) {
            s_h[q][2][node] = hreg[2];
            s_xe[q][node]   = proj;
            outp[((size_t)b * NNODE + node) * TT + t] = proj;
        }
        lds_barrier();
        dinp = proj; p = q;
    }
}

// ---------------- host launcher ---------------------------------------------
extern "C" void kernel_launch(void* const* d_in, const int* in_sizes, int n_in,
                              void* d_out, int out_size, void* d_ws, size_t ws_size,
                              hipStream_t stream)
{
    (void)in_sizes; (void)n_in; (void)out_size; (void)ws_size;
    const float* full_seq = (const float*)d_in[0];   // (M,64,8)
    const float* rec_seq  = (const float*)d_in[1];   // (32,360,64)
    const float* temp     = (const float*)d_in[3];
    const float* g0wih    = (const float*)d_in[4];
    const float* g0whh    = (const float*)d_in[5];
    const float* g0bih    = (const float*)d_in[6];
    const float* g0bhh    = (const float*)d_in[7];
    const float* gwih     = (const float*)d_in[8];   // (3,2,24,16)
    const float* gwhh     = (const float*)d_in[9];   // (3,2,24,8)
    const float* gbih     = (const float*)d_in[10];
    const float* gbhh     = (const float*)d_in[11];
    const float* l1w      = (const float*)d_in[12];
    const float* l1b      = (const float*)d_in[13];
    const float* l2w      = (const float*)d_in[14];
    const float* l2b      = (const float*)d_in[15];
    const float* enc_gw   = (const float*)d_in[16];
    const float* enc_gb   = (const float*)d_in[17];
    const float* enc_cw   = (const float*)d_in[18];
    const float* enc_cb   = (const float*)d_in[19];
    const float* dec_gw   = (const float*)d_in[20];
    const float* dec_gb   = (const float*)d_in[21];
    const float* dec_cw   = (const float*)d_in[22];
    const float* dec_cb   = (const float*)d_in[23];
    const float* proj_w   = (const float*)d_in[24];
    const float* proj_b   = (const float*)d_in[25];
    float* outp = (float*)d_out;

    // ws: small-first; bufA+bufB ping-pong = 94.85 MB total (proven size)
    float* ws   = (float*)d_ws;
    float* feat = ws;                                     // (M,8)
    float* vbuf = feat + (size_t)M_SEQ * 8;               // (M,)
    int*   cbuf = (int*)(vbuf + M_SEQ);                   // (M,)
    float* bufA = (float*)(cbuf + M_SEQ);                 // (M,64,16)
    float* bufB = bufA + (size_t)M_SEQ * TT * 16;         // (M,64,16)

    const int ggru = (M_SEQ * 2 * 8) / 256;   // 720 blocks
    gru_fused<8,false><<<ggru, 256, 0, stream>>>(full_seq, g0wih, g0whh, g0bih, g0bhh, bufA);
    gru_fused<16,false><<<ggru, 256, 0, stream>>>(bufA, gwih + 0 * 768, gwhh + 0 * 384,
                                                  gbih + 0 * 48, gbhh + 0 * 48, bufB);
    gru_fused<16,false><<<ggru, 256, 0, stream>>>(bufB, gwih + 1 * 768, gwhh + 1 * 384,
                                                  gbih + 1 * 48, gbhh + 1 * 48, bufA);
    gru_fused<16,true><<<ggru, 256, 0, stream>>>(bufA, gwih + 2 * 768, gwhh + 2 * 384,
                                                 gbih + 2 * 48, gbhh + 2 * 48, bufB);
    feat_kernel<<<M_SEQ / 256, 256, 0, stream>>>(bufB, l1w, l1b, l2w, l2b, feat);
    adj_kernel<<<(NB * NNODE) / 4, 256, 0, stream>>>(feat, temp, cbuf, vbuf);
    decode_kernel<<<NB, 768, 0, stream>>>(rec_seq, cbuf, vbuf,
                                          enc_gw, enc_gb, enc_cw, enc_cb,
                                          dec_gw, dec_gb, dec_cw, dec_cb,
                                          proj_w, proj_b, outp);
}